// Round 1
// baseline (2608.491 us; speedup 1.0000x reference)
//
#include <hip/hip_runtime.h>
#include <hip/hip_bf16.h>

#define NN 262144
#define EE 4194304
#define NG 16
#define NPER 16384
#define KK 7

__device__ __forceinline__ float wred(float v) {
    #pragma unroll
    for (int o = 32; o > 0; o >>= 1) v += __shfl_xor(v, o);
    return v;
}

// ---------- p normalization ----------
__global__ void prep_p(const float* __restrict__ p0, const float* __restrict__ p1,
                       float* __restrict__ pn) {
    int t = threadIdx.x; // 64 threads, 1 wave
    float v0 = (t < 32) ? p0[t] : 0.f;
    float s0 = wred(v0 * v0);
    if (t < 32) pn[t] = v0 * rsqrtf(s0);
    float v1 = p1[t];
    float s1 = wred(v1 * v1);
    pn[32 + t] = v1 * rsqrtf(s1);
}

// ---------- CSR build ----------
__global__ void count_edges(const int* __restrict__ ei, int* __restrict__ cnt) {
    int e = blockIdx.x * 256 + threadIdx.x;
    atomicAdd(&cnt[ei[EE + e]], 1);
}

__global__ void scan_block(const int* __restrict__ cnt, int* __restrict__ excl,
                           int* __restrict__ bsum) {
    __shared__ int sd[256];
    int t = threadIdx.x;
    int i = blockIdx.x * 256 + t;
    int v = cnt[i];
    sd[t] = v;
    __syncthreads();
    #pragma unroll
    for (int off = 1; off < 256; off <<= 1) {
        int add = (t >= off) ? sd[t - off] : 0;
        __syncthreads();
        sd[t] += add;
        __syncthreads();
    }
    excl[i] = sd[t] - v;
    if (t == 255) bsum[blockIdx.x] = sd[255];
}

__global__ void scan_partials(int* __restrict__ bsum) {
    __shared__ int sd[1024];
    int t = threadIdx.x;
    int v = bsum[t];
    sd[t] = v;
    __syncthreads();
    #pragma unroll
    for (int off = 1; off < 1024; off <<= 1) {
        int add = (t >= off) ? sd[t - off] : 0;
        __syncthreads();
        sd[t] += add;
        __syncthreads();
    }
    bsum[t] = sd[t] - v;
}

__global__ void scan_add(int* __restrict__ rowptr, const int* __restrict__ bsum,
                         int* __restrict__ wo) {
    int i = blockIdx.x * 256 + threadIdx.x;
    int v = rowptr[i] + bsum[blockIdx.x];
    rowptr[i] = v;
    wo[i] = v;
    if (i == 0) rowptr[NN] = EE;
}

__global__ void scatter_edges(const int* __restrict__ ei, const float* __restrict__ ew,
                              int* __restrict__ wo, int* __restrict__ srcs,
                              float* __restrict__ wsrt) {
    int e = blockIdx.x * 256 + threadIdx.x;
    int s = ei[e];
    int d = ei[EE + e];
    int pos = atomicAdd(&wo[d], 1);
    srcs[pos] = s;
    wsrt[pos] = ew[e];
}

__global__ void deg_kernel(const int* __restrict__ rowptr, const float* __restrict__ wsrt,
                           float* __restrict__ rsqd, float* __restrict__ invdeg) {
    int i = blockIdx.x * 256 + threadIdx.x;
    float s = 1.f;
    int e0 = rowptr[i], e1 = rowptr[i + 1];
    for (int e = e0; e < e1; ++e) s += wsrt[e];
    rsqd[i] = rsqrtf(s);
    invdeg[i] = 1.f / s;
}

// ---------- layer-0 scores ----------
__global__ void scores0_kernel(const float* __restrict__ x, const float* __restrict__ pn0,
                               float* __restrict__ scores) {
    __shared__ float p[32];
    if (threadIdx.x < 32) p[threadIdx.x] = pn0[threadIdx.x];
    __syncthreads();
    int n = blockIdx.x * 256 + threadIdx.x;
    const float4* xr = (const float4*)(x + (size_t)n * 32);
    float s = 0.f;
    #pragma unroll
    for (int j = 0; j < 8; j++) {
        float4 v = xr[j];
        s += v.x * p[j * 4] + v.y * p[j * 4 + 1] + v.z * p[j * 4 + 2] + v.w * p[j * 4 + 3];
    }
    scores[n] = s;
}

// ---------- per-graph top-7 ----------
__global__ void topk_kernel(const float* __restrict__ scores, float* __restrict__ topv,
                            int* __restrict__ topi) {
    int g = blockIdx.x;
    int t = threadIdx.x;
    float lv[KK];
    int li[KK];
    #pragma unroll
    for (int j = 0; j < KK; j++) { lv[j] = -INFINITY; li[j] = 0; }
    const float* sg = scores + (size_t)g * NPER;
    for (int it = 0; it < NPER / 256; ++it) {
        int idx = it * 256 + t;
        float v = sg[idx];
        if (v > lv[KK - 1]) {
            int j = KK - 1;
            while (j > 0 && lv[j - 1] < v) { lv[j] = lv[j - 1]; li[j] = li[j - 1]; j--; }
            lv[j] = v; li[j] = idx;
        }
    }
    __shared__ float sval[256];
    __shared__ int sidx[256];
    __shared__ int swin;
    int cons = 0;
    for (int r = 0; r < KK; r++) {
        sval[t] = (cons < KK) ? lv[cons] : -INFINITY;
        sidx[t] = t;
        __syncthreads();
        for (int s = 128; s > 0; s >>= 1) {
            if (t < s) {
                if (sval[t + s] > sval[t]) { sval[t] = sval[t + s]; sidx[t] = sidx[t + s]; }
            }
            __syncthreads();
        }
        if (t == 0) swin = sidx[0];
        __syncthreads();
        if (t == swin) {
            topv[g * KK + r] = lv[cons];
            topi[g * KK + r] = g * NPER + li[cons];
            cons++;
        }
        __syncthreads();
    }
}

// ---------- Z = mean_k tanh(s)*h[idx] ----------
__global__ void z_kernel(const float* __restrict__ h, int din, const float* __restrict__ topv,
                         const int* __restrict__ topi, float* __restrict__ Z) {
    int b = blockIdx.x;
    int d = threadIdx.x;
    if (d >= din) return;
    float acc = 0.f;
    for (int j = 0; j < KK; j++) {
        acc += tanhf(topv[b * KK + j]) * h[(size_t)topi[b * KK + j] * din + d];
    }
    Z[b * din + d] = acc * (1.f / 7.f);
}

// ---------- GRU: ghl[j,b] = sum_k Whh[j,k]*gh[b,k] (k-split, atomic combine) ----------
__global__ void gru_matvec(const float* __restrict__ Whh, const float* __restrict__ gh,
                           float* __restrict__ ghl, int P, int krange) {
    int j = blockIdx.x * 256 + threadIdx.x;
    int k0 = blockIdx.y * krange;
    float acc[16];
    #pragma unroll
    for (int b = 0; b < 16; b++) acc[b] = 0.f;
    const float4* wr = (const float4*)(Whh + (size_t)j * P + k0);
    int iters = krange >> 2;
    for (int kk = 0; kk < iters; ++kk) {
        float4 a = wr[kk];
        int kb = k0 + (kk << 2);
        #pragma unroll
        for (int b = 0; b < 16; b++) {
            float4 g = *(const float4*)(gh + (size_t)b * P + kb);
            acc[b] += a.x * g.x + a.y * g.y + a.z * g.z + a.w * g.w;
        }
    }
    #pragma unroll
    for (int b = 0; b < 16; b++) atomicAdd(&ghl[(size_t)j * 16 + b], acc[b]);
}

// ---------- GRU gates + evolved-W mean ----------
__global__ void gate_kernel(const float* __restrict__ Wih, const float* __restrict__ bih,
                            const float* __restrict__ bhh, const float* __restrict__ gh,
                            const float* __restrict__ ghl, const float* __restrict__ Zg,
                            float* __restrict__ Wev, int P, int din) {
    __shared__ float Zs[16 * 64];
    int t = threadIdx.x;
    for (int idx = t; idx < 16 * din; idx += 256) Zs[idx] = Zg[idx];
    __syncthreads();
    int p = blockIdx.x * 256 + t;
    float br = bih[p], bz = bih[P + p], bn = bih[2 * P + p];
    float bhr = bhh[p], bhz = bhh[P + p], bhn = bhh[2 * P + p];
    const float* w_r = Wih + (size_t)p * din;
    const float* w_z = Wih + (size_t)(P + p) * din;
    const float* w_n = Wih + (size_t)(2 * P + p) * din;
    float wsum = 0.f;
    for (int b = 0; b < 16; b++) {
        float ir = br, iz = bz, inn = bn;
        for (int d = 0; d < din; ++d) {
            float zd = Zs[b * din + d];
            ir += w_r[d] * zd;
            iz += w_z[d] * zd;
            inn += w_n[d] * zd;
        }
        float hr = ghl[(size_t)p * 16 + b] + bhr;
        float hz = ghl[(size_t)(P + p) * 16 + b] + bhz;
        float hn = ghl[(size_t)(2 * P + p) * 16 + b] + bhn;
        float r = 1.f / (1.f + expf(-(ir + hr)));
        float z = 1.f / (1.f + expf(-(iz + hz)));
        float n = tanhf(inn + r * hn);
        float hprev = gh[(size_t)b * P + p];
        wsum += (1.f - z) * n + z * hprev;
    }
    Wev[p] = wsum * (1.f / 16.f);
}

// ---------- edge aggregation on h (pre-linear), one wave per node ----------
__global__ void agg_kernel(const float* __restrict__ hin, int din,
                           const int* __restrict__ rowptr, const int* __restrict__ srcs,
                           const float* __restrict__ wsrt, const float* __restrict__ rsqd,
                           const float* __restrict__ invdeg, float* __restrict__ agg,
                           float* __restrict__ cc) {
    int t = threadIdx.x;
    int lane = t & 63;
    int i = blockIdx.x * 4 + (t >> 6);
    int e0 = rowptr[i], e1 = rowptr[i + 1];
    float rsi = rsqd[i];
    float acc = 0.f, csum = 0.f;
    for (int e = e0; e < e1; ++e) {
        int s = srcs[e];
        float nw = wsrt[e] * rsqd[s] * rsi;
        csum += nw;
        if (lane < din) acc += nw * hin[(size_t)s * din + lane];
    }
    float idg = invdeg[i];
    if (lane < din) {
        acc += hin[(size_t)i * din + lane] * idg;
        agg[(size_t)i * din + lane] = acc;
    }
    if (lane == 0) cc[i] = csum + idg;
}

// ---------- layer-0 epilogue: linear + LN + relu, fused layer-1 scores ----------
__global__ void post0_kernel(const float* __restrict__ agg, const float* __restrict__ cc,
                             const float* __restrict__ Wev, const float* __restrict__ gcnb,
                             const float* __restrict__ lng, const float* __restrict__ lnb,
                             const float* __restrict__ pn1, float* __restrict__ h1,
                             float* __restrict__ scores) {
    __shared__ float Wl[32 * 64];
    int t = threadIdx.x;
    for (int idx = t; idx < 2048; idx += 256) Wl[idx] = Wev[idx];
    __syncthreads();
    int lane = t & 63;
    int i = blockIdx.x * 4 + (t >> 6);
    const float* ar = agg + (size_t)i * 32;
    float val = gcnb[lane] * cc[i];
    #pragma unroll
    for (int d = 0; d < 32; ++d) val += ar[d] * Wl[d * 64 + lane];
    float mu = wred(val) * (1.f / 64.f);
    float dv = val - mu;
    float var = wred(dv * dv) * (1.f / 64.f);
    float y = dv * rsqrtf(var + 1e-5f) * lng[lane] + lnb[lane];
    float h = fmaxf(y, 0.f);
    h1[(size_t)i * 64 + lane] = h;
    float sc = wred(h * pn1[lane]);
    if (lane == 0) scores[i] = sc;
}

// ---------- layer-1 epilogue: linear + LN + relu + 5 prediction heads ----------
__global__ void post1_kernel(const float* __restrict__ agg, const float* __restrict__ cc,
                             const float* __restrict__ Wev, const float* __restrict__ gcnb,
                             const float* __restrict__ lng, const float* __restrict__ lnb,
                             const float* __restrict__ Wp, const float* __restrict__ bp,
                             float* __restrict__ out) {
    __shared__ float Wl[64 * 64];
    int t = threadIdx.x;
    for (int idx = t; idx < 4096; idx += 256) Wl[idx] = Wev[idx];
    __syncthreads();
    int lane = t & 63;
    int i = blockIdx.x * 4 + (t >> 6);
    const float* ar = agg + (size_t)i * 64;
    float val = gcnb[lane] * cc[i];
    #pragma unroll
    for (int d = 0; d < 64; ++d) val += ar[d] * Wl[d * 64 + lane];
    float mu = wred(val) * (1.f / 64.f);
    float dv = val - mu;
    float var = wred(dv * dv) * (1.f / 64.f);
    float y = dv * rsqrtf(var + 1e-5f) * lng[lane] + lnb[lane];
    float h = fmaxf(y, 0.f);
    float myout = 0.f;
    #pragma unroll
    for (int q = 0; q < 10; q++) {
        int s = q >> 1, o = q & 1;
        float wv = Wp[((s << 6) + lane) * 2 + o];
        float r = wred(h * wv);
        if (lane == q) myout = r + bp[q];
    }
    if (lane < 10) out[(size_t)i * 10 + lane] = myout;
}

extern "C" void kernel_launch(void* const* d_in, const int* in_sizes, int n_in,
                              void* d_out, int out_size, void* d_ws, size_t ws_size,
                              hipStream_t stream) {
    const float* x     = (const float*)d_in[0];
    const int*   ei    = (const int*)d_in[1];
    const float* ew    = (const float*)d_in[2];
    const float* p0    = (const float*)d_in[5];
    const float* p1    = (const float*)d_in[6];
    const float* Wih0  = (const float*)d_in[7];
    const float* Whh0  = (const float*)d_in[8];
    const float* bih0  = (const float*)d_in[9];
    const float* bhh0  = (const float*)d_in[10];
    const float* Wih1  = (const float*)d_in[11];
    const float* Whh1  = (const float*)d_in[12];
    const float* bih1  = (const float*)d_in[13];
    const float* bhh1  = (const float*)d_in[14];
    const float* gruh0 = (const float*)d_in[15];
    const float* gruh1 = (const float*)d_in[16];
    const float* gcnb0 = (const float*)d_in[17];
    const float* gcnb1 = (const float*)d_in[18];
    const float* lng0  = (const float*)d_in[19];
    const float* lnb0  = (const float*)d_in[20];
    const float* lng1  = (const float*)d_in[21];
    const float* lnb1  = (const float*)d_in[22];
    const float* Wp    = (const float*)d_in[23];
    const float* bp    = (const float*)d_in[24];
    float* out = (float*)d_out;

    // workspace carve (~175 MB)
    char* w = (char*)d_ws;
    size_t off = 0;
    auto alloc = [&](size_t bytes) -> void* {
        void* p = w + off;
        off += (bytes + 255) & ~(size_t)255;
        return p;
    };
    int*   rowptr = (int*)alloc((NN + 1) * sizeof(int));
    int*   wo     = (int*)alloc(NN * sizeof(int));
    int*   srcs   = (int*)alloc((size_t)EE * sizeof(int));
    float* wsrt   = (float*)alloc((size_t)EE * sizeof(float));
    float* rsqd   = (float*)alloc(NN * sizeof(float));
    float* invdeg = (float*)alloc(NN * sizeof(float));
    float* scores = (float*)alloc(NN * sizeof(float));
    float* topv   = (float*)alloc(NG * KK * sizeof(float));
    int*   topi   = (int*)alloc(NG * KK * sizeof(int));
    float* Z      = (float*)alloc(16 * 64 * sizeof(float));
    float* ghl    = (float*)alloc((size_t)12288 * 16 * sizeof(float));
    float* Wev    = (float*)alloc(4096 * sizeof(float));
    float* cc     = (float*)alloc(NN * sizeof(float));
    float* agg    = (float*)alloc((size_t)NN * 64 * sizeof(float));
    float* h1     = (float*)alloc((size_t)NN * 64 * sizeof(float));
    float* pn     = (float*)alloc(96 * sizeof(float));
    int*   bsum   = (int*)alloc(1024 * sizeof(int));

    // --- CSR build (shared by both layers) ---
    hipMemsetAsync(wo, 0, NN * sizeof(int), stream);
    prep_p<<<1, 64, 0, stream>>>(p0, p1, pn);
    count_edges<<<EE / 256, 256, 0, stream>>>(ei, wo);
    scan_block<<<NN / 256, 256, 0, stream>>>(wo, rowptr, bsum);
    scan_partials<<<1, 1024, 0, stream>>>(bsum);
    scan_add<<<NN / 256, 256, 0, stream>>>(rowptr, bsum, wo);
    scatter_edges<<<EE / 256, 256, 0, stream>>>(ei, ew, wo, srcs, wsrt);
    deg_kernel<<<NN / 256, 256, 0, stream>>>(rowptr, wsrt, rsqd, invdeg);

    // --- layer 0 ---
    scores0_kernel<<<NN / 256, 256, 0, stream>>>(x, pn, scores);
    topk_kernel<<<NG, 256, 0, stream>>>(scores, topv, topi);
    z_kernel<<<NG, 32, 0, stream>>>(x, 32, topv, topi, Z);
    hipMemsetAsync(ghl, 0, (size_t)6144 * 16 * sizeof(float), stream);
    gru_matvec<<<dim3(6144 / 256, 16), 256, 0, stream>>>(Whh0, gruh0, ghl, 2048, 128);
    gate_kernel<<<2048 / 256, 256, 0, stream>>>(Wih0, bih0, bhh0, gruh0, ghl, Z, Wev, 2048, 32);
    agg_kernel<<<NN / 4, 256, 0, stream>>>(x, 32, rowptr, srcs, wsrt, rsqd, invdeg, agg, cc);
    post0_kernel<<<NN / 4, 256, 0, stream>>>(agg, cc, Wev, gcnb0, lng0, lnb0, pn + 32, h1, scores);

    // --- layer 1 ---
    topk_kernel<<<NG, 256, 0, stream>>>(scores, topv, topi);
    z_kernel<<<NG, 64, 0, stream>>>(h1, 64, topv, topi, Z);
    hipMemsetAsync(ghl, 0, (size_t)12288 * 16 * sizeof(float), stream);
    gru_matvec<<<dim3(12288 / 256, 8), 256, 0, stream>>>(Whh1, gruh1, ghl, 4096, 512);
    gate_kernel<<<4096 / 256, 256, 0, stream>>>(Wih1, bih1, bhh1, gruh1, ghl, Z, Wev, 4096, 64);
    agg_kernel<<<NN / 4, 256, 0, stream>>>(h1, 64, rowptr, srcs, wsrt, rsqd, invdeg, agg, cc);
    post1_kernel<<<NN / 4, 256, 0, stream>>>(agg, cc, Wev, gcnb1, lng1, lnb1, Wp, bp, out);
}

// Round 2
// 2144.922 us; speedup vs baseline: 1.2161x; 1.2161x over previous
//
#include <hip/hip_runtime.h>
#include <hip/hip_bf16.h>

#define NN 262144
#define EE 4194304
#define NG 16
#define NPER 16384
#define KK 7

__device__ __forceinline__ float wred(float v) {
    #pragma unroll
    for (int o = 32; o > 0; o >>= 1) v += __shfl_xor(v, o);
    return v;
}

// ---------- p normalization ----------
__global__ void prep_p(const float* __restrict__ p0, const float* __restrict__ p1,
                       float* __restrict__ pn) {
    int t = threadIdx.x; // 64 threads, 1 wave
    float v0 = (t < 32) ? p0[t] : 0.f;
    float s0 = wred(v0 * v0);
    if (t < 32) pn[t] = v0 * rsqrtf(s0);
    float v1 = p1[t];
    float s1 = wred(v1 * v1);
    pn[32 + t] = v1 * rsqrtf(s1);
}

// ---------- CSR build ----------
// count + float-degree in one pass
__global__ void count_deg(const int* __restrict__ ei, const float* __restrict__ ew,
                          int* __restrict__ cnt, float* __restrict__ degf) {
    int e = blockIdx.x * 256 + threadIdx.x;
    int d = ei[EE + e];
    atomicAdd(&cnt[d], 1);
    atomicAdd(&degf[d], ew[e]);
}

__global__ void finalize_deg(const float* __restrict__ degf, float* __restrict__ rsqd,
                             float* __restrict__ invdeg) {
    int i = blockIdx.x * 256 + threadIdx.x;
    float s = degf[i] + 1.f;
    rsqd[i] = rsqrtf(s);
    invdeg[i] = 1.f / s;
}

__global__ void scan_block(const int* __restrict__ cnt, int* __restrict__ excl,
                           int* __restrict__ bsum) {
    __shared__ int sd[256];
    int t = threadIdx.x;
    int i = blockIdx.x * 256 + t;
    int v = cnt[i];
    sd[t] = v;
    __syncthreads();
    #pragma unroll
    for (int off = 1; off < 256; off <<= 1) {
        int add = (t >= off) ? sd[t - off] : 0;
        __syncthreads();
        sd[t] += add;
        __syncthreads();
    }
    excl[i] = sd[t] - v;
    if (t == 255) bsum[blockIdx.x] = sd[255];
}

__global__ void scan_partials(int* __restrict__ bsum) {
    __shared__ int sd[1024];
    int t = threadIdx.x;
    int v = bsum[t];
    sd[t] = v;
    __syncthreads();
    #pragma unroll
    for (int off = 1; off < 1024; off <<= 1) {
        int add = (t >= off) ? sd[t - off] : 0;
        __syncthreads();
        sd[t] += add;
        __syncthreads();
    }
    bsum[t] = sd[t] - v;
}

__global__ void scan_add(int* __restrict__ rowptr, const int* __restrict__ bsum,
                         int* __restrict__ wo) {
    int i = blockIdx.x * 256 + threadIdx.x;
    int v = rowptr[i] + bsum[blockIdx.x];
    rowptr[i] = v;
    wo[i] = v;
    if (i == 0) rowptr[NN] = EE;
}

// scatter with pre-scaled weight: w' = ew * rsqd[src]  (kills dependent load in agg)
__global__ void scatter_edges(const int* __restrict__ ei, const float* __restrict__ ew,
                              const float* __restrict__ rsqd, int* __restrict__ wo,
                              int2* __restrict__ evw) {
    int e = blockIdx.x * 256 + threadIdx.x;
    int s = ei[e];
    int d = ei[EE + e];
    float wt = ew[e] * rsqd[s];
    int pos = atomicAdd(&wo[d], 1);
    evw[pos] = make_int2(s, __float_as_int(wt));
}

// ---------- layer-0 scores ----------
__global__ void scores0_kernel(const float* __restrict__ x, const float* __restrict__ pn0,
                               float* __restrict__ scores) {
    __shared__ float p[32];
    if (threadIdx.x < 32) p[threadIdx.x] = pn0[threadIdx.x];
    __syncthreads();
    int n = blockIdx.x * 256 + threadIdx.x;
    const float4* xr = (const float4*)(x + (size_t)n * 32);
    float s = 0.f;
    #pragma unroll
    for (int j = 0; j < 8; j++) {
        float4 v = xr[j];
        s += v.x * p[j * 4] + v.y * p[j * 4 + 1] + v.z * p[j * 4 + 2] + v.w * p[j * 4 + 3];
    }
    scores[n] = s;
}

// ---------- per-graph top-7 ----------
__global__ void topk_kernel(const float* __restrict__ scores, float* __restrict__ topv,
                            int* __restrict__ topi) {
    int g = blockIdx.x;
    int t = threadIdx.x;
    float lv[KK];
    int li[KK];
    #pragma unroll
    for (int j = 0; j < KK; j++) { lv[j] = -INFINITY; li[j] = 0; }
    const float* sg = scores + (size_t)g * NPER;
    for (int it = 0; it < NPER / 256; ++it) {
        int idx = it * 256 + t;
        float v = sg[idx];
        if (v > lv[KK - 1]) {
            int j = KK - 1;
            while (j > 0 && lv[j - 1] < v) { lv[j] = lv[j - 1]; li[j] = li[j - 1]; j--; }
            lv[j] = v; li[j] = idx;
        }
    }
    __shared__ float sval[256];
    __shared__ int sidx[256];
    __shared__ int swin;
    int cons = 0;
    for (int r = 0; r < KK; r++) {
        sval[t] = (cons < KK) ? lv[cons] : -INFINITY;
        sidx[t] = t;
        __syncthreads();
        for (int s = 128; s > 0; s >>= 1) {
            if (t < s) {
                if (sval[t + s] > sval[t]) { sval[t] = sval[t + s]; sidx[t] = sidx[t + s]; }
            }
            __syncthreads();
        }
        if (t == 0) swin = sidx[0];
        __syncthreads();
        if (t == swin) {
            topv[g * KK + r] = lv[cons];
            topi[g * KK + r] = g * NPER + li[cons];
            cons++;
        }
        __syncthreads();
    }
}

// ---------- Z = mean_k tanh(s)*h[idx] ----------
__global__ void z_kernel(const float* __restrict__ h, int din, const float* __restrict__ topv,
                         const int* __restrict__ topi, float* __restrict__ Z) {
    int b = blockIdx.x;
    int d = threadIdx.x;
    if (d >= din) return;
    float acc = 0.f;
    for (int j = 0; j < KK; j++) {
        acc += tanhf(topv[b * KK + j]) * h[(size_t)topi[b * KK + j] * din + d];
    }
    Z[b * din + d] = acc * (1.f / 7.f);
}

// ---------- GRU: ghl[j,b] = sum_k Whh[j,k]*gh[b,k] ----------
// 16 lanes per row, coalesced 256B Whh reads, shfl-reduce, k-split via blockIdx.y (KR=512)
__global__ void gru_matvec(const float* __restrict__ Whh, const float* __restrict__ gh,
                           float* __restrict__ ghl, int P) {
    int t = threadIdx.x;
    int g = t >> 4, l16 = t & 15;
    int row = blockIdx.x * 16 + g;
    int k0 = blockIdx.y * 512;
    float acc[16];
    #pragma unroll
    for (int b = 0; b < 16; b++) acc[b] = 0.f;
    const float* wr = Whh + (size_t)row * P + k0 + l16 * 4;
    const float* gr = gh + k0 + l16 * 4;
    #pragma unroll 2
    for (int kk = 0; kk < 8; ++kk) {
        float4 a = *(const float4*)(wr + kk * 64);
        #pragma unroll
        for (int b = 0; b < 16; b++) {
            float4 gv = *(const float4*)(gr + (size_t)b * P + kk * 64);
            acc[b] += a.x * gv.x + a.y * gv.y + a.z * gv.z + a.w * gv.w;
        }
    }
    #pragma unroll
    for (int b = 0; b < 16; b++) {
        float v = acc[b];
        v += __shfl_xor(v, 1); v += __shfl_xor(v, 2);
        v += __shfl_xor(v, 4); v += __shfl_xor(v, 8);
        if (l16 == b) atomicAdd(&ghl[(size_t)row * 16 + b], v);
    }
}

// ---------- GRU gates + evolved-W mean ----------
__global__ void gate_kernel(const float* __restrict__ Wih, const float* __restrict__ bih,
                            const float* __restrict__ bhh, const float* __restrict__ gh,
                            const float* __restrict__ ghl, const float* __restrict__ Zg,
                            float* __restrict__ Wev, int P, int din) {
    __shared__ float Zs[16 * 64];
    int t = threadIdx.x;
    for (int idx = t; idx < 16 * din; idx += 256) Zs[idx] = Zg[idx];
    __syncthreads();
    int p = blockIdx.x * 256 + t;
    float br = bih[p], bz = bih[P + p], bn = bih[2 * P + p];
    float bhr = bhh[p], bhz = bhh[P + p], bhn = bhh[2 * P + p];
    const float* w_r = Wih + (size_t)p * din;
    const float* w_z = Wih + (size_t)(P + p) * din;
    const float* w_n = Wih + (size_t)(2 * P + p) * din;
    float wsum = 0.f;
    for (int b = 0; b < 16; b++) {
        float ir = br, iz = bz, inn = bn;
        for (int d = 0; d < din; ++d) {
            float zd = Zs[b * din + d];
            ir += w_r[d] * zd;
            iz += w_z[d] * zd;
            inn += w_n[d] * zd;
        }
        float hr = ghl[(size_t)p * 16 + b] + bhr;
        float hz = ghl[(size_t)(P + p) * 16 + b] + bhz;
        float hn = ghl[(size_t)(2 * P + p) * 16 + b] + bhn;
        float r = 1.f / (1.f + expf(-(ir + hr)));
        float z = 1.f / (1.f + expf(-(iz + hz)));
        float n = tanhf(inn + r * hn);
        float hprev = gh[(size_t)b * P + p];
        wsum += (1.f - z) * n + z * hprev;
    }
    Wev[p] = wsum * (1.f / 16.f);
}

// ---------- edge aggregation on h (pre-linear), one wave per node, unroll-8 ----------
template<int DIN>
__global__ void agg_kernel(const float* __restrict__ hin,
                           const int* __restrict__ rowptr, const int2* __restrict__ evw,
                           const float* __restrict__ rsqd, const float* __restrict__ invdeg,
                           float* __restrict__ agg, float* __restrict__ cc) {
    int t = threadIdx.x;
    int lane = t & 63;
    int i = blockIdx.x * 4 + (t >> 6);
    int e0 = rowptr[i], e1 = rowptr[i + 1];
    float acc = 0.f, csum = 0.f;
    for (int e = e0; e < e1; e += 8) {
        int2 ev[8];
        #pragma unroll
        for (int j = 0; j < 8; j++) {
            ev[j] = (e + j < e1) ? evw[e + j] : make_int2(i, 0);
        }
        float v[8];
        #pragma unroll
        for (int j = 0; j < 8; j++) {
            v[j] = (lane < DIN) ? hin[(size_t)ev[j].x * DIN + lane] : 0.f;
        }
        #pragma unroll
        for (int j = 0; j < 8; j++) {
            float nw = __int_as_float(ev[j].y);
            csum += nw;
            acc += nw * v[j];
        }
    }
    float rsi = rsqd[i];
    float idg = invdeg[i];
    if (lane < DIN) {
        float r = acc * rsi + hin[(size_t)i * DIN + lane] * idg;
        agg[(size_t)i * DIN + lane] = r;
    }
    if (lane == 0) cc[i] = csum * rsi + idg;
}

// ---------- layer-0 epilogue: linear + LN + relu, fused layer-1 scores ----------
__global__ void post0_kernel(const float* __restrict__ agg, const float* __restrict__ cc,
                             const float* __restrict__ Wev, const float* __restrict__ gcnb,
                             const float* __restrict__ lng, const float* __restrict__ lnb,
                             const float* __restrict__ pn1, float* __restrict__ h1,
                             float* __restrict__ scores) {
    __shared__ float Wl[32 * 64];
    int t = threadIdx.x;
    for (int idx = t; idx < 2048; idx += 256) Wl[idx] = Wev[idx];
    __syncthreads();
    int lane = t & 63;
    int i = blockIdx.x * 4 + (t >> 6);
    const float* ar = agg + (size_t)i * 32;
    float val = gcnb[lane] * cc[i];
    #pragma unroll
    for (int d = 0; d < 32; ++d) val += ar[d] * Wl[d * 64 + lane];
    float mu = wred(val) * (1.f / 64.f);
    float dv = val - mu;
    float var = wred(dv * dv) * (1.f / 64.f);
    float y = dv * rsqrtf(var + 1e-5f) * lng[lane] + lnb[lane];
    float h = fmaxf(y, 0.f);
    h1[(size_t)i * 64 + lane] = h;
    float sc = wred(h * pn1[lane]);
    if (lane == 0) scores[i] = sc;
}

// ---------- layer-1 epilogue: linear + LN + relu + 5 prediction heads ----------
__global__ void post1_kernel(const float* __restrict__ agg, const float* __restrict__ cc,
                             const float* __restrict__ Wev, const float* __restrict__ gcnb,
                             const float* __restrict__ lng, const float* __restrict__ lnb,
                             const float* __restrict__ Wp, const float* __restrict__ bp,
                             float* __restrict__ out) {
    __shared__ float Wl[64 * 64];
    int t = threadIdx.x;
    for (int idx = t; idx < 4096; idx += 256) Wl[idx] = Wev[idx];
    __syncthreads();
    int lane = t & 63;
    int i = blockIdx.x * 4 + (t >> 6);
    const float* ar = agg + (size_t)i * 64;
    float val = gcnb[lane] * cc[i];
    #pragma unroll
    for (int d = 0; d < 64; ++d) val += ar[d] * Wl[d * 64 + lane];
    float mu = wred(val) * (1.f / 64.f);
    float dv = val - mu;
    float var = wred(dv * dv) * (1.f / 64.f);
    float y = dv * rsqrtf(var + 1e-5f) * lng[lane] + lnb[lane];
    float h = fmaxf(y, 0.f);
    float myout = 0.f;
    #pragma unroll
    for (int q = 0; q < 10; q++) {
        int s = q >> 1, o = q & 1;
        float wv = Wp[((s << 6) + lane) * 2 + o];
        float r = wred(h * wv);
        if (lane == q) myout = r + bp[q];
    }
    if (lane < 10) out[(size_t)i * 10 + lane] = myout;
}

extern "C" void kernel_launch(void* const* d_in, const int* in_sizes, int n_in,
                              void* d_out, int out_size, void* d_ws, size_t ws_size,
                              hipStream_t stream) {
    const float* x     = (const float*)d_in[0];
    const int*   ei    = (const int*)d_in[1];
    const float* ew    = (const float*)d_in[2];
    const float* p0    = (const float*)d_in[5];
    const float* p1    = (const float*)d_in[6];
    const float* Wih0  = (const float*)d_in[7];
    const float* Whh0  = (const float*)d_in[8];
    const float* bih0  = (const float*)d_in[9];
    const float* bhh0  = (const float*)d_in[10];
    const float* Wih1  = (const float*)d_in[11];
    const float* Whh1  = (const float*)d_in[12];
    const float* bih1  = (const float*)d_in[13];
    const float* bhh1  = (const float*)d_in[14];
    const float* gruh0 = (const float*)d_in[15];
    const float* gruh1 = (const float*)d_in[16];
    const float* gcnb0 = (const float*)d_in[17];
    const float* gcnb1 = (const float*)d_in[18];
    const float* lng0  = (const float*)d_in[19];
    const float* lnb0  = (const float*)d_in[20];
    const float* lng1  = (const float*)d_in[21];
    const float* lnb1  = (const float*)d_in[22];
    const float* Wp    = (const float*)d_in[23];
    const float* bp    = (const float*)d_in[24];
    float* out = (float*)d_out;

    // workspace carve
    char* w = (char*)d_ws;
    size_t off = 0;
    auto alloc = [&](size_t bytes) -> void* {
        void* p = w + off;
        off += (bytes + 255) & ~(size_t)255;
        return p;
    };
    int*   rowptr = (int*)alloc((NN + 1) * sizeof(int));
    int*   wo     = (int*)alloc(NN * sizeof(int));
    int2*  evw    = (int2*)alloc((size_t)EE * sizeof(int2));
    float* degf   = (float*)alloc(NN * sizeof(float));
    float* rsqd   = (float*)alloc(NN * sizeof(float));
    float* invdeg = (float*)alloc(NN * sizeof(float));
    float* scores = (float*)alloc(NN * sizeof(float));
    float* topv   = (float*)alloc(NG * KK * sizeof(float));
    int*   topi   = (int*)alloc(NG * KK * sizeof(int));
    float* Z      = (float*)alloc(16 * 64 * sizeof(float));
    float* ghl    = (float*)alloc((size_t)12288 * 16 * sizeof(float));
    float* Wev    = (float*)alloc(4096 * sizeof(float));
    float* cc     = (float*)alloc(NN * sizeof(float));
    float* agg    = (float*)alloc((size_t)NN * 64 * sizeof(float));
    float* h1     = (float*)alloc((size_t)NN * 64 * sizeof(float));
    float* pn     = (float*)alloc(96 * sizeof(float));
    int*   bsum   = (int*)alloc(1024 * sizeof(int));

    // --- CSR build (shared by both layers) ---
    hipMemsetAsync(wo, 0, NN * sizeof(int), stream);
    hipMemsetAsync(degf, 0, NN * sizeof(float), stream);
    prep_p<<<1, 64, 0, stream>>>(p0, p1, pn);
    count_deg<<<EE / 256, 256, 0, stream>>>(ei, ew, wo, degf);
    finalize_deg<<<NN / 256, 256, 0, stream>>>(degf, rsqd, invdeg);
    scan_block<<<NN / 256, 256, 0, stream>>>(wo, rowptr, bsum);
    scan_partials<<<1, 1024, 0, stream>>>(bsum);
    scan_add<<<NN / 256, 256, 0, stream>>>(rowptr, bsum, wo);
    scatter_edges<<<EE / 256, 256, 0, stream>>>(ei, ew, rsqd, wo, evw);

    // --- layer 0 ---
    scores0_kernel<<<NN / 256, 256, 0, stream>>>(x, pn, scores);
    topk_kernel<<<NG, 256, 0, stream>>>(scores, topv, topi);
    z_kernel<<<NG, 32, 0, stream>>>(x, 32, topv, topi, Z);
    hipMemsetAsync(ghl, 0, (size_t)6144 * 16 * sizeof(float), stream);
    gru_matvec<<<dim3(6144 / 16, 4), 256, 0, stream>>>(Whh0, gruh0, ghl, 2048);
    gate_kernel<<<2048 / 256, 256, 0, stream>>>(Wih0, bih0, bhh0, gruh0, ghl, Z, Wev, 2048, 32);
    agg_kernel<32><<<NN / 4, 256, 0, stream>>>(x, rowptr, evw, rsqd, invdeg, agg, cc);
    post0_kernel<<<NN / 4, 256, 0, stream>>>(agg, cc, Wev, gcnb0, lng0, lnb0, pn + 32, h1, scores);

    // --- layer 1 ---
    topk_kernel<<<NG, 256, 0, stream>>>(scores, topv, topi);
    z_kernel<<<NG, 64, 0, stream>>>(h1, 64, topv, topi, Z);
    hipMemsetAsync(ghl, 0, (size_t)12288 * 16 * sizeof(float), stream);
    gru_matvec<<<dim3(12288 / 16, 8), 256, 0, stream>>>(Whh1, gruh1, ghl, 4096);
    gate_kernel<<<4096 / 256, 256, 0, stream>>>(Wih1, bih1, bhh1, gruh1, ghl, Z, Wev, 4096, 64);
    agg_kernel<64><<<NN / 4, 256, 0, stream>>>(h1, rowptr, evw, rsqd, invdeg, agg, cc);
    post1_kernel<<<NN / 4, 256, 0, stream>>>(agg, cc, Wev, gcnb1, lng1, lnb1, Wp, bp, out);
}

// Round 3
// 1974.365 us; speedup vs baseline: 1.3212x; 1.0864x over previous
//
#include <hip/hip_runtime.h>
#include <hip/hip_bf16.h>

#define NN 262144
#define EE 4194304
#define NG 16
#define NPER 16384
#define KK 7

__device__ __forceinline__ float wred(float v) {
    #pragma unroll
    for (int o = 32; o > 0; o >>= 1) v += __shfl_xor(v, o);
    return v;
}

// ---------- p normalization ----------
__global__ void prep_p(const float* __restrict__ p0, const float* __restrict__ p1,
                       float* __restrict__ pn) {
    int t = threadIdx.x; // 64 threads, 1 wave
    float v0 = (t < 32) ? p0[t] : 0.f;
    float s0 = wred(v0 * v0);
    if (t < 32) pn[t] = v0 * rsqrtf(s0);
    float v1 = p1[t];
    float s1 = wred(v1 * v1);
    pn[32 + t] = v1 * rsqrtf(s1);
}

// ---------- CSR build, XCD-privatized ----------
// One u64 atomic per edge: count in bits >=40, fixed-point (2^-24) weight sum in low 40.
// x = blockIdx&7 is deterministic per edge AND matches round-robin block->XCD mapping,
// so each [x] slice's lines stay in one XCD's L2 (no cross-XCD ping-pong).
__global__ void count64(const int* __restrict__ ei, const float* __restrict__ ew,
                        unsigned long long* __restrict__ bins) {
    int e = blockIdx.x * 256 + threadIdx.x;
    int d = ei[EE + e];
    unsigned long long v = (1ULL << 40) |
        (unsigned long long)(unsigned int)__float2uint_rn(ew[e] * 16777216.0f);
    atomicAdd(&bins[(size_t)(blockIdx.x & 7) * NN + d], v);
}

// reduce 8 planes -> per-node count (block-scanned) + degree (rsqd/invdeg)
__global__ void scan_block_bins(const unsigned long long* __restrict__ bins,
                                int* __restrict__ rowptr, int* __restrict__ bsum,
                                float* __restrict__ rsqd, float* __restrict__ invdeg) {
    __shared__ int sd[256];
    int t = threadIdx.x;
    int i = blockIdx.x * 256 + t;
    unsigned long long s = 0;
    #pragma unroll
    for (int x = 0; x < 8; x++) s += bins[(size_t)x * NN + i];
    int v = (int)(s >> 40);
    float deg = 1.f + (float)(s & ((1ULL << 40) - 1)) * (1.f / 16777216.f);
    rsqd[i] = rsqrtf(deg);
    invdeg[i] = 1.f / deg;
    sd[t] = v;
    __syncthreads();
    #pragma unroll
    for (int off = 1; off < 256; off <<= 1) {
        int add = (t >= off) ? sd[t - off] : 0;
        __syncthreads();
        sd[t] += add;
        __syncthreads();
    }
    rowptr[i] = sd[t] - v;
    if (t == 255) bsum[blockIdx.x] = sd[255];
}

__global__ void scan_partials(int* __restrict__ bsum) {
    __shared__ int sd[1024];
    int t = threadIdx.x;
    int v = bsum[t];
    sd[t] = v;
    __syncthreads();
    #pragma unroll
    for (int off = 1; off < 1024; off <<= 1) {
        int add = (t >= off) ? sd[t - off] : 0;
        __syncthreads();
        sd[t] += add;
        __syncthreads();
    }
    bsum[t] = sd[t] - v;
}

__global__ void scan_add(int* __restrict__ rowptr, const int* __restrict__ bsum) {
    int i = blockIdx.x * 256 + threadIdx.x;
    rowptr[i] += bsum[blockIdx.x];
    if (i == 0) rowptr[NN] = EE;
}

// per-node cursor start for each xcd slice: rowptr[n] + prefix of per-slice counts
__global__ void cursor_init(const unsigned long long* __restrict__ bins,
                            const int* __restrict__ rowptr, int* __restrict__ cursor) {
    int n = blockIdx.x * 256 + threadIdx.x;
    int base = rowptr[n];
    #pragma unroll
    for (int x = 0; x < 8; x++) {
        cursor[(size_t)x * NN + n] = base;
        base += (int)(bins[(size_t)x * NN + n] >> 40);
    }
}

// scatter with pre-scaled weight: w' = ew * rsqd[src]; XCD-local position atomics
__global__ void scatter_edges(const int* __restrict__ ei, const float* __restrict__ ew,
                              const float* __restrict__ rsqd, int* __restrict__ cursor,
                              int2* __restrict__ evw) {
    int e = blockIdx.x * 256 + threadIdx.x;
    int s = ei[e];
    int d = ei[EE + e];
    float wt = ew[e] * rsqd[s];
    int pos = atomicAdd(&cursor[(size_t)(blockIdx.x & 7) * NN + d], 1);
    evw[pos] = make_int2(s, __float_as_int(wt));
}

// ---------- layer-0 scores ----------
__global__ void scores0_kernel(const float* __restrict__ x, const float* __restrict__ pn0,
                               float* __restrict__ scores) {
    __shared__ float p[32];
    if (threadIdx.x < 32) p[threadIdx.x] = pn0[threadIdx.x];
    __syncthreads();
    int n = blockIdx.x * 256 + threadIdx.x;
    const float4* xr = (const float4*)(x + (size_t)n * 32);
    float s = 0.f;
    #pragma unroll
    for (int j = 0; j < 8; j++) {
        float4 v = xr[j];
        s += v.x * p[j * 4] + v.y * p[j * 4 + 1] + v.z * p[j * 4 + 2] + v.w * p[j * 4 + 3];
    }
    scores[n] = s;
}

// ---------- per-graph top-7 ----------
__global__ void topk_kernel(const float* __restrict__ scores, float* __restrict__ topv,
                            int* __restrict__ topi) {
    int g = blockIdx.x;
    int t = threadIdx.x;
    float lv[KK];
    int li[KK];
    #pragma unroll
    for (int j = 0; j < KK; j++) { lv[j] = -INFINITY; li[j] = 0; }
    const float* sg = scores + (size_t)g * NPER;
    for (int it = 0; it < NPER / 256; ++it) {
        int idx = it * 256 + t;
        float v = sg[idx];
        if (v > lv[KK - 1]) {
            int j = KK - 1;
            while (j > 0 && lv[j - 1] < v) { lv[j] = lv[j - 1]; li[j] = li[j - 1]; j--; }
            lv[j] = v; li[j] = idx;
        }
    }
    __shared__ float sval[256];
    __shared__ int sidx[256];
    __shared__ int swin;
    int cons = 0;
    for (int r = 0; r < KK; r++) {
        sval[t] = (cons < KK) ? lv[cons] : -INFINITY;
        sidx[t] = t;
        __syncthreads();
        for (int s = 128; s > 0; s >>= 1) {
            if (t < s) {
                if (sval[t + s] > sval[t]) { sval[t] = sval[t + s]; sidx[t] = sidx[t + s]; }
            }
            __syncthreads();
        }
        if (t == 0) swin = sidx[0];
        __syncthreads();
        if (t == swin) {
            topv[g * KK + r] = lv[cons];
            topi[g * KK + r] = g * NPER + li[cons];
            cons++;
        }
        __syncthreads();
    }
}

// ---------- Z = mean_k tanh(s)*h[idx] ----------
__global__ void z_kernel(const float* __restrict__ h, int din, const float* __restrict__ topv,
                         const int* __restrict__ topi, float* __restrict__ Z) {
    int b = blockIdx.x;
    int d = threadIdx.x;
    if (d >= din) return;
    float acc = 0.f;
    for (int j = 0; j < KK; j++) {
        acc += tanhf(topv[b * KK + j]) * h[(size_t)topi[b * KK + j] * din + d];
    }
    Z[b * din + d] = acc * (1.f / 7.f);
}

// ---------- GRU: ghl[j,b] = sum_k Whh[j,k]*gh[b,k] ----------
__global__ void gru_matvec(const float* __restrict__ Whh, const float* __restrict__ gh,
                           float* __restrict__ ghl, int P) {
    int t = threadIdx.x;
    int g = t >> 4, l16 = t & 15;
    int row = blockIdx.x * 16 + g;
    int k0 = blockIdx.y * 512;
    float acc[16];
    #pragma unroll
    for (int b = 0; b < 16; b++) acc[b] = 0.f;
    const float* wr = Whh + (size_t)row * P + k0 + l16 * 4;
    const float* gr = gh + k0 + l16 * 4;
    #pragma unroll 2
    for (int kk = 0; kk < 8; ++kk) {
        float4 a = *(const float4*)(wr + kk * 64);
        #pragma unroll
        for (int b = 0; b < 16; b++) {
            float4 gv = *(const float4*)(gr + (size_t)b * P + kk * 64);
            acc[b] += a.x * gv.x + a.y * gv.y + a.z * gv.z + a.w * gv.w;
        }
    }
    #pragma unroll
    for (int b = 0; b < 16; b++) {
        float v = acc[b];
        v += __shfl_xor(v, 1); v += __shfl_xor(v, 2);
        v += __shfl_xor(v, 4); v += __shfl_xor(v, 8);
        if (l16 == b) atomicAdd(&ghl[(size_t)row * 16 + b], v);
    }
}

// ---------- GRU gates + evolved-W mean ----------
__global__ void gate_kernel(const float* __restrict__ Wih, const float* __restrict__ bih,
                            const float* __restrict__ bhh, const float* __restrict__ gh,
                            const float* __restrict__ ghl, const float* __restrict__ Zg,
                            float* __restrict__ Wev, int P, int din) {
    __shared__ float Zs[16 * 64];
    int t = threadIdx.x;
    for (int idx = t; idx < 16 * din; idx += 256) Zs[idx] = Zg[idx];
    __syncthreads();
    int p = blockIdx.x * 256 + t;
    float br = bih[p], bz = bih[P + p], bn = bih[2 * P + p];
    float bhr = bhh[p], bhz = bhh[P + p], bhn = bhh[2 * P + p];
    const float* w_r = Wih + (size_t)p * din;
    const float* w_z = Wih + (size_t)(P + p) * din;
    const float* w_n = Wih + (size_t)(2 * P + p) * din;
    float wsum = 0.f;
    for (int b = 0; b < 16; b++) {
        float ir = br, iz = bz, inn = bn;
        for (int d = 0; d < din; ++d) {
            float zd = Zs[b * din + d];
            ir += w_r[d] * zd;
            iz += w_z[d] * zd;
            inn += w_n[d] * zd;
        }
        float hr = ghl[(size_t)p * 16 + b] + bhr;
        float hz = ghl[(size_t)(P + p) * 16 + b] + bhz;
        float hn = ghl[(size_t)(2 * P + p) * 16 + b] + bhn;
        float r = 1.f / (1.f + expf(-(ir + hr)));
        float z = 1.f / (1.f + expf(-(iz + hz)));
        float n = tanhf(inn + r * hn);
        float hprev = gh[(size_t)b * P + p];
        wsum += (1.f - z) * n + z * hprev;
    }
    Wev[p] = wsum * (1.f / 16.f);
}

// ---------- edge aggregation on h (pre-linear), one wave per node, unroll-8 ----------
template<int DIN>
__global__ void agg_kernel(const float* __restrict__ hin,
                           const int* __restrict__ rowptr, const int2* __restrict__ evw,
                           const float* __restrict__ rsqd, const float* __restrict__ invdeg,
                           float* __restrict__ agg, float* __restrict__ cc) {
    int t = threadIdx.x;
    int lane = t & 63;
    int i = blockIdx.x * 4 + (t >> 6);
    int e0 = rowptr[i], e1 = rowptr[i + 1];
    float acc = 0.f, csum = 0.f;
    for (int e = e0; e < e1; e += 8) {
        int2 ev[8];
        #pragma unroll
        for (int j = 0; j < 8; j++) {
            ev[j] = (e + j < e1) ? evw[e + j] : make_int2(i, 0);
        }
        float v[8];
        #pragma unroll
        for (int j = 0; j < 8; j++) {
            v[j] = (lane < DIN) ? hin[(size_t)ev[j].x * DIN + lane] : 0.f;
        }
        #pragma unroll
        for (int j = 0; j < 8; j++) {
            float nw = __int_as_float(ev[j].y);
            csum += nw;
            acc += nw * v[j];
        }
    }
    float rsi = rsqd[i];
    float idg = invdeg[i];
    if (lane < DIN) {
        float r = acc * rsi + hin[(size_t)i * DIN + lane] * idg;
        agg[(size_t)i * DIN + lane] = r;
    }
    if (lane == 0) cc[i] = csum * rsi + idg;
}

// ---------- layer-0 epilogue: linear + LN + relu, fused layer-1 scores ----------
__global__ void post0_kernel(const float* __restrict__ agg, const float* __restrict__ cc,
                             const float* __restrict__ Wev, const float* __restrict__ gcnb,
                             const float* __restrict__ lng, const float* __restrict__ lnb,
                             const float* __restrict__ pn1, float* __restrict__ h1,
                             float* __restrict__ scores) {
    __shared__ float Wl[32 * 64];
    int t = threadIdx.x;
    for (int idx = t; idx < 2048; idx += 256) Wl[idx] = Wev[idx];
    __syncthreads();
    int lane = t & 63;
    int i = blockIdx.x * 4 + (t >> 6);
    const float* ar = agg + (size_t)i * 32;
    float val = gcnb[lane] * cc[i];
    #pragma unroll
    for (int d = 0; d < 32; ++d) val += ar[d] * Wl[d * 64 + lane];
    float mu = wred(val) * (1.f / 64.f);
    float dv = val - mu;
    float var = wred(dv * dv) * (1.f / 64.f);
    float y = dv * rsqrtf(var + 1e-5f) * lng[lane] + lnb[lane];
    float h = fmaxf(y, 0.f);
    h1[(size_t)i * 64 + lane] = h;
    float sc = wred(h * pn1[lane]);
    if (lane == 0) scores[i] = sc;
}

// ---------- layer-1 epilogue: linear + LN + relu + 5 prediction heads ----------
__global__ void post1_kernel(const float* __restrict__ agg, const float* __restrict__ cc,
                             const float* __restrict__ Wev, const float* __restrict__ gcnb,
                             const float* __restrict__ lng, const float* __restrict__ lnb,
                             const float* __restrict__ Wp, const float* __restrict__ bp,
                             float* __restrict__ out) {
    __shared__ float Wl[64 * 64];
    int t = threadIdx.x;
    for (int idx = t; idx < 4096; idx += 256) Wl[idx] = Wev[idx];
    __syncthreads();
    int lane = t & 63;
    int i = blockIdx.x * 4 + (t >> 6);
    const float* ar = agg + (size_t)i * 64;
    float val = gcnb[lane] * cc[i];
    #pragma unroll
    for (int d = 0; d < 64; ++d) val += ar[d] * Wl[d * 64 + lane];
    float mu = wred(val) * (1.f / 64.f);
    float dv = val - mu;
    float var = wred(dv * dv) * (1.f / 64.f);
    float y = dv * rsqrtf(var + 1e-5f) * lng[lane] + lnb[lane];
    float h = fmaxf(y, 0.f);
    float myout = 0.f;
    #pragma unroll
    for (int q = 0; q < 10; q++) {
        int s = q >> 1, o = q & 1;
        float wv = Wp[((s << 6) + lane) * 2 + o];
        float r = wred(h * wv);
        if (lane == q) myout = r + bp[q];
    }
    if (lane < 10) out[(size_t)i * 10 + lane] = myout;
}

extern "C" void kernel_launch(void* const* d_in, const int* in_sizes, int n_in,
                              void* d_out, int out_size, void* d_ws, size_t ws_size,
                              hipStream_t stream) {
    const float* x     = (const float*)d_in[0];
    const int*   ei    = (const int*)d_in[1];
    const float* ew    = (const float*)d_in[2];
    const float* p0    = (const float*)d_in[5];
    const float* p1    = (const float*)d_in[6];
    const float* Wih0  = (const float*)d_in[7];
    const float* Whh0  = (const float*)d_in[8];
    const float* bih0  = (const float*)d_in[9];
    const float* bhh0  = (const float*)d_in[10];
    const float* Wih1  = (const float*)d_in[11];
    const float* Whh1  = (const float*)d_in[12];
    const float* bih1  = (const float*)d_in[13];
    const float* bhh1  = (const float*)d_in[14];
    const float* gruh0 = (const float*)d_in[15];
    const float* gruh1 = (const float*)d_in[16];
    const float* gcnb0 = (const float*)d_in[17];
    const float* gcnb1 = (const float*)d_in[18];
    const float* lng0  = (const float*)d_in[19];
    const float* lnb0  = (const float*)d_in[20];
    const float* lng1  = (const float*)d_in[21];
    const float* lnb1  = (const float*)d_in[22];
    const float* Wp    = (const float*)d_in[23];
    const float* bp    = (const float*)d_in[24];
    float* out = (float*)d_out;

    // workspace carve
    char* w = (char*)d_ws;
    size_t off = 0;
    auto alloc = [&](size_t bytes) -> void* {
        void* p = w + off;
        off += (bytes + 255) & ~(size_t)255;
        return p;
    };
    int*   rowptr = (int*)alloc((NN + 1) * sizeof(int));
    int2*  evw    = (int2*)alloc((size_t)EE * sizeof(int2));
    float* rsqd   = (float*)alloc(NN * sizeof(float));
    float* invdeg = (float*)alloc(NN * sizeof(float));
    float* scores = (float*)alloc(NN * sizeof(float));
    float* topv   = (float*)alloc(NG * KK * sizeof(float));
    int*   topi   = (int*)alloc(NG * KK * sizeof(int));
    float* Z      = (float*)alloc(16 * 64 * sizeof(float));
    float* ghl    = (float*)alloc((size_t)12288 * 16 * sizeof(float));
    float* Wev    = (float*)alloc(4096 * sizeof(float));
    float* cc     = (float*)alloc(NN * sizeof(float));
    float* agg    = (float*)alloc((size_t)NN * 64 * sizeof(float));
    float* h1     = (float*)alloc((size_t)NN * 64 * sizeof(float));
    float* pn     = (float*)alloc(96 * sizeof(float));
    int*   bsum   = (int*)alloc(1024 * sizeof(int));

    // bins64 (16 MB) + cursor (8 MB) alias into agg's 67 MB (dead before agg is written)
    unsigned long long* bins64 = (unsigned long long*)agg;
    int* cursor = (int*)((char*)agg + (size_t)8 * NN * sizeof(unsigned long long));

    // --- CSR build (shared by both layers), XCD-privatized ---
    hipMemsetAsync(bins64, 0, (size_t)8 * NN * sizeof(unsigned long long), stream);
    prep_p<<<1, 64, 0, stream>>>(p0, p1, pn);
    count64<<<EE / 256, 256, 0, stream>>>(ei, ew, bins64);
    scan_block_bins<<<NN / 256, 256, 0, stream>>>(bins64, rowptr, bsum, rsqd, invdeg);
    scan_partials<<<1, 1024, 0, stream>>>(bsum);
    scan_add<<<NN / 256, 256, 0, stream>>>(rowptr, bsum);
    cursor_init<<<NN / 256, 256, 0, stream>>>(bins64, rowptr, cursor);
    scatter_edges<<<EE / 256, 256, 0, stream>>>(ei, ew, rsqd, cursor, evw);

    // --- layer 0 ---
    scores0_kernel<<<NN / 256, 256, 0, stream>>>(x, pn, scores);
    topk_kernel<<<NG, 256, 0, stream>>>(scores, topv, topi);
    z_kernel<<<NG, 32, 0, stream>>>(x, 32, topv, topi, Z);
    hipMemsetAsync(ghl, 0, (size_t)6144 * 16 * sizeof(float), stream);
    gru_matvec<<<dim3(6144 / 16, 4), 256, 0, stream>>>(Whh0, gruh0, ghl, 2048);
    gate_kernel<<<2048 / 256, 256, 0, stream>>>(Wih0, bih0, bhh0, gruh0, ghl, Z, Wev, 2048, 32);
    agg_kernel<32><<<NN / 4, 256, 0, stream>>>(x, rowptr, evw, rsqd, invdeg, agg, cc);
    post0_kernel<<<NN / 4, 256, 0, stream>>>(agg, cc, Wev, gcnb0, lng0, lnb0, pn + 32, h1, scores);

    // --- layer 1 ---
    topk_kernel<<<NG, 256, 0, stream>>>(scores, topv, topi);
    z_kernel<<<NG, 64, 0, stream>>>(h1, 64, topv, topi, Z);
    hipMemsetAsync(ghl, 0, (size_t)12288 * 16 * sizeof(float), stream);
    gru_matvec<<<dim3(12288 / 16, 8), 256, 0, stream>>>(Whh1, gruh1, ghl, 4096);
    gate_kernel<<<4096 / 256, 256, 0, stream>>>(Wih1, bih1, bhh1, gruh1, ghl, Z, Wev, 4096, 64);
    agg_kernel<64><<<NN / 4, 256, 0, stream>>>(h1, rowptr, evw, rsqd, invdeg, agg, cc);
    post1_kernel<<<NN / 4, 256, 0, stream>>>(agg, cc, Wev, gcnb1, lng1, lnb1, Wp, bp, out);
}

// Round 5
// 1699.728 us; speedup vs baseline: 1.5347x; 1.1616x over previous
//
#include <hip/hip_runtime.h>
#include <hip/hip_bf16.h>

#define NN 262144
#define EE 4194304
#define NG 16
#define NPER 16384
#define KK 7
#define TPAD 20

__device__ __forceinline__ float wred(float v) {
    #pragma unroll
    for (int o = 32; o > 0; o >>= 1) v += __shfl_xor(v, o);
    return v;
}

// ---------- p normalization ----------
__global__ void prep_p(const float* __restrict__ p0, const float* __restrict__ p1,
                       float* __restrict__ pn) {
    int t = threadIdx.x; // 64 threads, 1 wave
    float v0 = (t < 32) ? p0[t] : 0.f;
    float s0 = wred(v0 * v0);
    if (t < 32) pn[t] = v0 * rsqrtf(s0);
    float v1 = p1[t];
    float s1 = wred(v1 * v1);
    pn[32 + t] = v1 * rsqrtf(s1);
}

// ---------- CSR build, XCD-privatized ----------
__global__ void count64(const int* __restrict__ ei, const float* __restrict__ ew,
                        unsigned long long* __restrict__ bins) {
    int e = blockIdx.x * 256 + threadIdx.x;
    int d = ei[EE + e];
    unsigned long long v = (1ULL << 40) |
        (unsigned long long)(unsigned int)__float2uint_rn(ew[e] * 16777216.0f);
    atomicAdd(&bins[(size_t)(blockIdx.x & 7) * NN + d], v);
}

__global__ void scan_block_bins(const unsigned long long* __restrict__ bins,
                                int* __restrict__ rowptr, int* __restrict__ bsum,
                                float* __restrict__ rsqd, float* __restrict__ invdeg) {
    __shared__ int sd[256];
    int t = threadIdx.x;
    int i = blockIdx.x * 256 + t;
    unsigned long long s = 0;
    #pragma unroll
    for (int x = 0; x < 8; x++) s += bins[(size_t)x * NN + i];
    int v = (int)(s >> 40);
    float deg = 1.f + (float)(s & ((1ULL << 40) - 1)) * (1.f / 16777216.f);
    rsqd[i] = rsqrtf(deg);
    invdeg[i] = 1.f / deg;
    sd[t] = v;
    __syncthreads();
    #pragma unroll
    for (int off = 1; off < 256; off <<= 1) {
        int add = (t >= off) ? sd[t - off] : 0;
        __syncthreads();
        sd[t] += add;
        __syncthreads();
    }
    rowptr[i] = sd[t] - v;
    if (t == 255) bsum[blockIdx.x] = sd[255];
}

__global__ void scan_partials(int* __restrict__ bsum) {
    __shared__ int sd[1024];
    int t = threadIdx.x;
    int v = bsum[t];
    sd[t] = v;
    __syncthreads();
    #pragma unroll
    for (int off = 1; off < 1024; off <<= 1) {
        int add = (t >= off) ? sd[t - off] : 0;
        __syncthreads();
        sd[t] += add;
        __syncthreads();
    }
    bsum[t] = sd[t] - v;
}

__global__ void scan_add(int* __restrict__ rowptr, const int* __restrict__ bsum) {
    int i = blockIdx.x * 256 + threadIdx.x;
    rowptr[i] += bsum[blockIdx.x];
    if (i == 0) rowptr[NN] = EE;
}

__global__ void cursor_init(const unsigned long long* __restrict__ bins,
                            const int* __restrict__ rowptr, int* __restrict__ cursor) {
    int n = blockIdx.x * 256 + threadIdx.x;
    int base = rowptr[n];
    #pragma unroll
    for (int x = 0; x < 8; x++) {
        cursor[(size_t)x * NN + n] = base;
        base += (int)(bins[(size_t)x * NN + n] >> 40);
    }
}

__global__ void scatter_edges(const int* __restrict__ ei, const float* __restrict__ ew,
                              const float* __restrict__ rsqd, int* __restrict__ cursor,
                              int2* __restrict__ evw) {
    int e = blockIdx.x * 256 + threadIdx.x;
    int s = ei[e];
    int d = ei[EE + e];
    float wt = ew[e] * rsqd[s];
    int pos = atomicAdd(&cursor[(size_t)(blockIdx.x & 7) * NN + d], 1);
    evw[pos] = make_int2(s, __float_as_int(wt));
}

// ---------- layer-0 scores ----------
__global__ void scores0_kernel(const float* __restrict__ x, const float* __restrict__ pn0,
                               float* __restrict__ scores) {
    __shared__ float p[32];
    if (threadIdx.x < 32) p[threadIdx.x] = pn0[threadIdx.x];
    __syncthreads();
    int n = blockIdx.x * 256 + threadIdx.x;
    const float4* xr = (const float4*)(x + (size_t)n * 32);
    float s = 0.f;
    #pragma unroll
    for (int j = 0; j < 8; j++) {
        float4 v = xr[j];
        s += v.x * p[j * 4] + v.y * p[j * 4 + 1] + v.z * p[j * 4 + 2] + v.w * p[j * 4 + 3];
    }
    scores[n] = s;
}

// ---------- per-graph top-7 ----------
__global__ void topk_kernel(const float* __restrict__ scores, float* __restrict__ topv,
                            int* __restrict__ topi) {
    int g = blockIdx.x;
    int t = threadIdx.x;
    float lv[KK];
    int li[KK];
    #pragma unroll
    for (int j = 0; j < KK; j++) { lv[j] = -INFINITY; li[j] = 0; }
    const float* sg = scores + (size_t)g * NPER;
    for (int it = 0; it < NPER / 256; ++it) {
        int idx = it * 256 + t;
        float v = sg[idx];
        if (v > lv[KK - 1]) {
            int j = KK - 1;
            while (j > 0 && lv[j - 1] < v) { lv[j] = lv[j - 1]; li[j] = li[j - 1]; j--; }
            lv[j] = v; li[j] = idx;
        }
    }
    __shared__ float sval[256];
    __shared__ int sidx[256];
    __shared__ int swin;
    int cons = 0;
    for (int r = 0; r < KK; r++) {
        sval[t] = (cons < KK) ? lv[cons] : -INFINITY;
        sidx[t] = t;
        __syncthreads();
        for (int s = 128; s > 0; s >>= 1) {
            if (t < s) {
                if (sval[t + s] > sval[t]) { sval[t] = sval[t + s]; sidx[t] = sidx[t + s]; }
            }
            __syncthreads();
        }
        if (t == 0) swin = sidx[0];
        __syncthreads();
        if (t == swin) {
            topv[g * KK + r] = lv[cons];
            topi[g * KK + r] = g * NPER + li[cons];
            cons++;
        }
        __syncthreads();
    }
}

// ---------- Z = mean_k tanh(s)*h[idx] ----------
__global__ void z_kernel(const float* __restrict__ h, int din, const float* __restrict__ topv,
                         const int* __restrict__ topi, float* __restrict__ Z) {
    int b = blockIdx.x;
    int d = threadIdx.x;
    if (d >= din) return;
    float acc = 0.f;
    for (int j = 0; j < KK; j++) {
        acc += tanhf(topv[b * KK + j]) * h[(size_t)topi[b * KK + j] * din + d];
    }
    Z[b * din + d] = acc * (1.f / 7.f);
}

// ---------- GRU: ghl[j,b] = sum_k Whh[j,k]*gh[b,k] ----------
__global__ void gru_matvec(const float* __restrict__ Whh, const float* __restrict__ gh,
                           float* __restrict__ ghl, int P) {
    int t = threadIdx.x;
    int g = t >> 4, l16 = t & 15;
    int row = blockIdx.x * 16 + g;
    int k0 = blockIdx.y * 512;
    float acc[16];
    #pragma unroll
    for (int b = 0; b < 16; b++) acc[b] = 0.f;
    const float* wr = Whh + (size_t)row * P + k0 + l16 * 4;
    const float* gr = gh + k0 + l16 * 4;
    #pragma unroll 2
    for (int kk = 0; kk < 8; ++kk) {
        float4 a = *(const float4*)(wr + kk * 64);
        #pragma unroll
        for (int b = 0; b < 16; b++) {
            float4 gv = *(const float4*)(gr + (size_t)b * P + kk * 64);
            acc[b] += a.x * gv.x + a.y * gv.y + a.z * gv.z + a.w * gv.w;
        }
    }
    #pragma unroll
    for (int b = 0; b < 16; b++) {
        float v = acc[b];
        v += __shfl_xor(v, 1); v += __shfl_xor(v, 2);
        v += __shfl_xor(v, 4); v += __shfl_xor(v, 8);
        if (l16 == b) atomicAdd(&ghl[(size_t)row * 16 + b], v);
    }
}

// ---------- GRU gates + evolved-W mean ----------
__global__ void gate_kernel(const float* __restrict__ Wih, const float* __restrict__ bih,
                            const float* __restrict__ bhh, const float* __restrict__ gh,
                            const float* __restrict__ ghl, const float* __restrict__ Zg,
                            float* __restrict__ Wev, int P, int din) {
    __shared__ float Zs[16 * 64];
    int t = threadIdx.x;
    for (int idx = t; idx < 16 * din; idx += 256) Zs[idx] = Zg[idx];
    __syncthreads();
    int p = blockIdx.x * 256 + t;
    float br = bih[p], bz = bih[P + p], bn = bih[2 * P + p];
    float bhr = bhh[p], bhz = bhh[P + p], bhn = bhh[2 * P + p];
    const float* w_r = Wih + (size_t)p * din;
    const float* w_z = Wih + (size_t)(P + p) * din;
    const float* w_n = Wih + (size_t)(2 * P + p) * din;
    float wsum = 0.f;
    for (int b = 0; b < 16; b++) {
        float ir = br, iz = bz, inn = bn;
        for (int d = 0; d < din; ++d) {
            float zd = Zs[b * din + d];
            ir += w_r[d] * zd;
            iz += w_z[d] * zd;
            inn += w_n[d] * zd;
        }
        float hr = ghl[(size_t)p * 16 + b] + bhr;
        float hz = ghl[(size_t)(P + p) * 16 + b] + bhz;
        float hn = ghl[(size_t)(2 * P + p) * 16 + b] + bhn;
        float r = 1.f / (1.f + expf(-(ir + hr)));
        float z = 1.f / (1.f + expf(-(iz + hz)));
        float n = tanhf(inn + r * hn);
        float hprev = gh[(size_t)b * P + p];
        wsum += (1.f - z) * n + z * hprev;
    }
    Wev[p] = wsum * (1.f / 16.f);
}

// ---------- edge aggregation: LSH=5 -> 32 lanes/node (DIN=32), LSH=6 -> 64 ----------
template<int DIN, int LSH>
__global__ void agg_kernel(const float* __restrict__ hin,
                           const int* __restrict__ rowptr, const int2* __restrict__ evw,
                           const float* __restrict__ rsqd, const float* __restrict__ invdeg,
                           float* __restrict__ agg, float* __restrict__ cc) {
    int t = threadIdx.x;
    int lane = t & ((1 << LSH) - 1);
    int i = blockIdx.x * (256 >> LSH) + (t >> LSH);
    int e0 = rowptr[i], e1 = rowptr[i + 1];
    float acc = 0.f, csum = 0.f;
    for (int e = e0; e < e1; e += 8) {
        int2 ev[8];
        #pragma unroll
        for (int j = 0; j < 8; j++) {
            ev[j] = (e + j < e1) ? evw[e + j] : make_int2(i, 0);
        }
        float v[8];
        #pragma unroll
        for (int j = 0; j < 8; j++) {
            v[j] = hin[(size_t)ev[j].x * DIN + lane];
        }
        #pragma unroll
        for (int j = 0; j < 8; j++) {
            float nw = __int_as_float(ev[j].y);
            csum += nw;
            acc += nw * v[j];
        }
    }
    float rsi = rsqd[i];
    float idg = invdeg[i];
    float r = acc * rsi + hin[(size_t)i * DIN + lane] * idg;
    agg[(size_t)i * DIN + lane] = r;
    #pragma unroll
    for (int o = (1 << LSH) >> 1; o > 0; o >>= 1) csum += __shfl_xor(csum, o);
    if (lane == 0) cc[i] = csum * rsi + idg;
}

// ---------- post kernels: 1 wave = 64-node tile, lane = outdim ----------
// GEMM agg[tile]@W via wave-uniform agg reads + coalesced W column loads;
// LN + epilogue in registers after one small LDS transpose. Plain TPAD=20 padding:
// read pattern is a 4-way bank conflict (~1.58x on 16 scalar ds_reads) - negligible;
// the previous +16 intra-row offset trick OVERFLOWED the 20-slot row (race) - removed.

__global__ __launch_bounds__(64) void post0_kernel(
    const float* __restrict__ agg, const float* __restrict__ cc,
    const float* __restrict__ Wev, const float* __restrict__ gcnb,
    const float* __restrict__ lng, const float* __restrict__ lnb,
    const float* __restrict__ pn1, float* __restrict__ h1,
    float* __restrict__ scores) {
    __shared__ float tile[64 * TPAD];
    const int lane = threadIdx.x;
    const int tb = blockIdx.x * 64;
    const int j = lane & 15, q = lane >> 4;
    float v0[16], v1[16], v2[16], v3[16];
    #pragma unroll
    for (int k = 0; k < 16; k++) { v0[k] = 0.f; v1[k] = 0.f; v2[k] = 0.f; v3[k] = 0.f; }
    for (int db = 0; db < 8; ++db) {
        float wc0 = Wev[(db * 4 + 0) * 64 + lane];
        float wc1 = Wev[(db * 4 + 1) * 64 + lane];
        float wc2 = Wev[(db * 4 + 2) * 64 + lane];
        float wc3 = Wev[(db * 4 + 3) * 64 + lane];
        #pragma unroll
        for (int k = 0; k < 16; k++) {
            float4 a = *(const float4*)(agg + (size_t)(tb + k) * 32 + db * 4);
            v0[k] += a.x * wc0 + a.y * wc1 + a.z * wc2 + a.w * wc3;
        }
        #pragma unroll
        for (int k = 0; k < 16; k++) {
            float4 a = *(const float4*)(agg + (size_t)(tb + 16 + k) * 32 + db * 4);
            v1[k] += a.x * wc0 + a.y * wc1 + a.z * wc2 + a.w * wc3;
        }
        #pragma unroll
        for (int k = 0; k < 16; k++) {
            float4 a = *(const float4*)(agg + (size_t)(tb + 32 + k) * 32 + db * 4);
            v2[k] += a.x * wc0 + a.y * wc1 + a.z * wc2 + a.w * wc3;
        }
        #pragma unroll
        for (int k = 0; k < 16; k++) {
            float4 a = *(const float4*)(agg + (size_t)(tb + 48 + k) * 32 + db * 4);
            v3[k] += a.x * wc0 + a.y * wc1 + a.z * wc2 + a.w * wc3;
        }
    }
    float gL = gcnb[lane];
    float lgv[16], lbv[16], pnv[16];
    #pragma unroll
    for (int r = 0; r < 16; r++) {
        lgv[r] = lng[q * 16 + r];
        lbv[r] = lnb[q * 16 + r];
        pnv[r] = pn1[q * 16 + r];
    }
    float* trow = tile + lane * TPAD;
    auto do_chunk = [&](float (&VV)[16], int C) {
        __syncthreads();
        #pragma unroll
        for (int k = 0; k < 16; k++) trow[k] = VV[k] + gL * cc[tb + C * 16 + k];
        __syncthreads();
        float av[16];
        #pragma unroll
        for (int r = 0; r < 16; r++) av[r] = tile[(q * 16 + r) * TPAD + j];
        float s1 = 0.f, s2 = 0.f;
        #pragma unroll
        for (int r = 0; r < 16; r++) { s1 += av[r]; s2 += av[r] * av[r]; }
        s1 += __shfl_xor(s1, 16); s1 += __shfl_xor(s1, 32);
        s2 += __shfl_xor(s2, 16); s2 += __shfl_xor(s2, 32);
        float mu = s1 * (1.f / 64.f);
        float rstd = rsqrtf(s2 * (1.f / 64.f) - mu * mu + 1e-5f);
        float hv[16];
        float sc = 0.f;
        #pragma unroll
        for (int r = 0; r < 16; r++) {
            hv[r] = fmaxf((av[r] - mu) * rstd * lgv[r] + lbv[r], 0.f);
            sc += hv[r] * pnv[r];
        }
        int node = tb + C * 16 + j;
        #pragma unroll
        for (int k = 0; k < 16; k += 4)
            *(float4*)(h1 + (size_t)node * 64 + q * 16 + k) =
                make_float4(hv[k], hv[k + 1], hv[k + 2], hv[k + 3]);
        sc += __shfl_xor(sc, 16); sc += __shfl_xor(sc, 32);
        if (q == 0) scores[node] = sc;
    };
    do_chunk(v0, 0); do_chunk(v1, 1); do_chunk(v2, 2); do_chunk(v3, 3);
}

__global__ __launch_bounds__(64) void post1_kernel(
    const float* __restrict__ agg, const float* __restrict__ cc,
    const float* __restrict__ Wev, const float* __restrict__ gcnb,
    const float* __restrict__ lng, const float* __restrict__ lnb,
    const float* __restrict__ Wp, const float* __restrict__ bp,
    float* __restrict__ out) {
    __shared__ float tile[64 * TPAD];
    const int lane = threadIdx.x;
    const int tb = blockIdx.x * 64;
    const int j = lane & 15, q = lane >> 4;
    float v0[16], v1[16], v2[16], v3[16];
    #pragma unroll
    for (int k = 0; k < 16; k++) { v0[k] = 0.f; v1[k] = 0.f; v2[k] = 0.f; v3[k] = 0.f; }
    for (int db = 0; db < 16; ++db) {
        float wc0 = Wev[(db * 4 + 0) * 64 + lane];
        float wc1 = Wev[(db * 4 + 1) * 64 + lane];
        float wc2 = Wev[(db * 4 + 2) * 64 + lane];
        float wc3 = Wev[(db * 4 + 3) * 64 + lane];
        #pragma unroll
        for (int k = 0; k < 16; k++) {
            float4 a = *(const float4*)(agg + (size_t)(tb + k) * 64 + db * 4);
            v0[k] += a.x * wc0 + a.y * wc1 + a.z * wc2 + a.w * wc3;
        }
        #pragma unroll
        for (int k = 0; k < 16; k++) {
            float4 a = *(const float4*)(agg + (size_t)(tb + 16 + k) * 64 + db * 4);
            v1[k] += a.x * wc0 + a.y * wc1 + a.z * wc2 + a.w * wc3;
        }
        #pragma unroll
        for (int k = 0; k < 16; k++) {
            float4 a = *(const float4*)(agg + (size_t)(tb + 32 + k) * 64 + db * 4);
            v2[k] += a.x * wc0 + a.y * wc1 + a.z * wc2 + a.w * wc3;
        }
        #pragma unroll
        for (int k = 0; k < 16; k++) {
            float4 a = *(const float4*)(agg + (size_t)(tb + 48 + k) * 64 + db * 4);
            v3[k] += a.x * wc0 + a.y * wc1 + a.z * wc2 + a.w * wc3;
        }
    }
    float gL = gcnb[lane];
    float lgv[16], lbv[16];
    #pragma unroll
    for (int r = 0; r < 16; r++) {
        lgv[r] = lng[q * 16 + r];
        lbv[r] = lnb[q * 16 + r];
    }
    float bpv[10];
    #pragma unroll
    for (int t2 = 0; t2 < 10; t2++) bpv[t2] = bp[t2];
    float* trow = tile + lane * TPAD;
    auto do_chunk = [&](float (&VV)[16], int C) {
        __syncthreads();
        #pragma unroll
        for (int k = 0; k < 16; k++) trow[k] = VV[k] + gL * cc[tb + C * 16 + k];
        __syncthreads();
        float av[16];
        #pragma unroll
        for (int r = 0; r < 16; r++) av[r] = tile[(q * 16 + r) * TPAD + j];
        float s1 = 0.f, s2 = 0.f;
        #pragma unroll
        for (int r = 0; r < 16; r++) { s1 += av[r]; s2 += av[r] * av[r]; }
        s1 += __shfl_xor(s1, 16); s1 += __shfl_xor(s1, 32);
        s2 += __shfl_xor(s2, 16); s2 += __shfl_xor(s2, 32);
        float mu = s1 * (1.f / 64.f);
        float rstd = rsqrtf(s2 * (1.f / 64.f) - mu * mu + 1e-5f);
        float hv[16];
        #pragma unroll
        for (int r = 0; r < 16; r++)
            hv[r] = fmaxf((av[r] - mu) * rstd * lgv[r] + lbv[r], 0.f);
        float oa[10];
        #pragma unroll
        for (int t2 = 0; t2 < 10; t2++) oa[t2] = 0.f;
        #pragma unroll
        for (int r = 0; r < 16; r++) {
            const float* wpb = Wp + (size_t)(q * 16 + r) * 2;
            float2 w0 = *(const float2*)(wpb);
            float2 w1 = *(const float2*)(wpb + 128);
            float2 w2 = *(const float2*)(wpb + 256);
            float2 w3 = *(const float2*)(wpb + 384);
            float2 w4 = *(const float2*)(wpb + 512);
            oa[0] += hv[r] * w0.x; oa[1] += hv[r] * w0.y;
            oa[2] += hv[r] * w1.x; oa[3] += hv[r] * w1.y;
            oa[4] += hv[r] * w2.x; oa[5] += hv[r] * w2.y;
            oa[6] += hv[r] * w3.x; oa[7] += hv[r] * w3.y;
            oa[8] += hv[r] * w4.x; oa[9] += hv[r] * w4.y;
        }
        #pragma unroll
        for (int t2 = 0; t2 < 10; t2++) {
            oa[t2] += __shfl_xor(oa[t2], 16);
            oa[t2] += __shfl_xor(oa[t2], 32);
        }
        if (q == 0) {
            int node = tb + C * 16 + j;
            #pragma unroll
            for (int t2 = 0; t2 < 10; t2++) out[(size_t)node * 10 + t2] = oa[t2] + bpv[t2];
        }
    };
    do_chunk(v0, 0); do_chunk(v1, 1); do_chunk(v2, 2); do_chunk(v3, 3);
}

extern "C" void kernel_launch(void* const* d_in, const int* in_sizes, int n_in,
                              void* d_out, int out_size, void* d_ws, size_t ws_size,
                              hipStream_t stream) {
    const float* x     = (const float*)d_in[0];
    const int*   ei    = (const int*)d_in[1];
    const float* ew    = (const float*)d_in[2];
    const float* p0    = (const float*)d_in[5];
    const float* p1    = (const float*)d_in[6];
    const float* Wih0  = (const float*)d_in[7];
    const float* Whh0  = (const float*)d_in[8];
    const float* bih0  = (const float*)d_in[9];
    const float* bhh0  = (const float*)d_in[10];
    const float* Wih1  = (const float*)d_in[11];
    const float* Whh1  = (const float*)d_in[12];
    const float* bih1  = (const float*)d_in[13];
    const float* bhh1  = (const float*)d_in[14];
    const float* gruh0 = (const float*)d_in[15];
    const float* gruh1 = (const float*)d_in[16];
    const float* gcnb0 = (const float*)d_in[17];
    const float* gcnb1 = (const float*)d_in[18];
    const float* lng0  = (const float*)d_in[19];
    const float* lnb0  = (const float*)d_in[20];
    const float* lng1  = (const float*)d_in[21];
    const float* lnb1  = (const float*)d_in[22];
    const float* Wp    = (const float*)d_in[23];
    const float* bp    = (const float*)d_in[24];
    float* out = (float*)d_out;

    // workspace carve
    char* w = (char*)d_ws;
    size_t off = 0;
    auto alloc = [&](size_t bytes) -> void* {
        void* p = w + off;
        off += (bytes + 255) & ~(size_t)255;
        return p;
    };
    int*   rowptr = (int*)alloc((NN + 1) * sizeof(int));
    int2*  evw    = (int2*)alloc((size_t)EE * sizeof(int2));
    float* rsqd   = (float*)alloc(NN * sizeof(float));
    float* invdeg = (float*)alloc(NN * sizeof(float));
    float* scores = (float*)alloc(NN * sizeof(float));
    float* topv   = (float*)alloc(NG * KK * sizeof(float));
    int*   topi   = (int*)alloc(NG * KK * sizeof(int));
    float* Z      = (float*)alloc(16 * 64 * sizeof(float));
    float* ghl    = (float*)alloc((size_t)12288 * 16 * sizeof(float));
    float* Wev    = (float*)alloc(4096 * sizeof(float));
    float* cc     = (float*)alloc(NN * sizeof(float));
    float* agg    = (float*)alloc((size_t)NN * 64 * sizeof(float));
    float* h1     = (float*)alloc((size_t)NN * 64 * sizeof(float));
    float* pn     = (float*)alloc(96 * sizeof(float));
    int*   bsum   = (int*)alloc(1024 * sizeof(int));

    // bins64 (16 MB) + cursor (8 MB) alias into agg's 67 MB (dead before agg is written)
    unsigned long long* bins64 = (unsigned long long*)agg;
    int* cursor = (int*)((char*)agg + (size_t)8 * NN * sizeof(unsigned long long));

    // --- CSR build (shared by both layers), XCD-privatized ---
    hipMemsetAsync(bins64, 0, (size_t)8 * NN * sizeof(unsigned long long), stream);
    prep_p<<<1, 64, 0, stream>>>(p0, p1, pn);
    count64<<<EE / 256, 256, 0, stream>>>(ei, ew, bins64);
    scan_block_bins<<<NN / 256, 256, 0, stream>>>(bins64, rowptr, bsum, rsqd, invdeg);
    scan_partials<<<1, 1024, 0, stream>>>(bsum);
    scan_add<<<NN / 256, 256, 0, stream>>>(rowptr, bsum);
    cursor_init<<<NN / 256, 256, 0, stream>>>(bins64, rowptr, cursor);
    scatter_edges<<<EE / 256, 256, 0, stream>>>(ei, ew, rsqd, cursor, evw);

    // --- layer 0 ---
    scores0_kernel<<<NN / 256, 256, 0, stream>>>(x, pn, scores);
    topk_kernel<<<NG, 256, 0, stream>>>(scores, topv, topi);
    z_kernel<<<NG, 32, 0, stream>>>(x, 32, topv, topi, Z);
    hipMemsetAsync(ghl, 0, (size_t)6144 * 16 * sizeof(float), stream);
    gru_matvec<<<dim3(6144 / 16, 4), 256, 0, stream>>>(Whh0, gruh0, ghl, 2048);
    gate_kernel<<<2048 / 256, 256, 0, stream>>>(Wih0, bih0, bhh0, gruh0, ghl, Z, Wev, 2048, 32);
    agg_kernel<32, 5><<<NN / 8, 256, 0, stream>>>(x, rowptr, evw, rsqd, invdeg, agg, cc);
    post0_kernel<<<NN / 64, 64, 0, stream>>>(agg, cc, Wev, gcnb0, lng0, lnb0, pn + 32, h1, scores);

    // --- layer 1 ---
    topk_kernel<<<NG, 256, 0, stream>>>(scores, topv, topi);
    z_kernel<<<NG, 64, 0, stream>>>(h1, 64, topv, topi, Z);
    hipMemsetAsync(ghl, 0, (size_t)12288 * 16 * sizeof(float), stream);
    gru_matvec<<<dim3(12288 / 16, 8), 256, 0, stream>>>(Whh1, gruh1, ghl, 4096);
    gate_kernel<<<4096 / 256, 256, 0, stream>>>(Wih1, bih1, bhh1, gruh1, ghl, Z, Wev, 4096, 64);
    agg_kernel<64, 6><<<NN / 4, 256, 0, stream>>>(h1, rowptr, evw, rsqd, invdeg, agg, cc);
    post1_kernel<<<NN / 64, 64, 0, stream>>>(agg, cc, Wev, gcnb1, lng1, lnb1, Wp, bp, out);
}

// Round 7
// 1676.592 us; speedup vs baseline: 1.5558x; 1.0138x over previous
//
#include <hip/hip_runtime.h>
#include <hip/hip_bf16.h>
#include <hip/hip_fp16.h>

#define NN 262144
#define EE 4194304
#define NG 16
#define NPER 16384
#define KK 7
#define TPAD 20

__device__ __forceinline__ float wred(float v) {
    #pragma unroll
    for (int o = 32; o > 0; o >>= 1) v += __shfl_xor(v, o);
    return v;
}

__device__ __forceinline__ unsigned short f2h(float f) {
    return __half_as_ushort(__float2half_rn(f));
}
__device__ __forceinline__ float h2f(unsigned short s) {
    return __half2float(__ushort_as_half(s));
}

// ---------- p normalization ----------
__global__ void prep_p(const float* __restrict__ p0, const float* __restrict__ p1,
                       float* __restrict__ pn) {
    int t = threadIdx.x; // 64 threads, 1 wave
    float v0 = (t < 32) ? p0[t] : 0.f;
    float s0 = wred(v0 * v0);
    if (t < 32) pn[t] = v0 * rsqrtf(s0);
    float v1 = p1[t];
    float s1 = wred(v1 * v1);
    pn[32 + t] = v1 * rsqrtf(s1);
}

// ---------- f32 -> f16 conversion (8 elements/thread) ----------
__global__ void to_f16(const float* __restrict__ in, unsigned short* __restrict__ outp) {
    size_t i = ((size_t)blockIdx.x * 256 + threadIdx.x) * 8;
    float4 a = *(const float4*)(in + i);
    float4 b = *(const float4*)(in + i + 4);
    uint4 o;
    o.x = (unsigned)f2h(a.x) | ((unsigned)f2h(a.y) << 16);
    o.y = (unsigned)f2h(a.z) | ((unsigned)f2h(a.w) << 16);
    o.z = (unsigned)f2h(b.x) | ((unsigned)f2h(b.y) << 16);
    o.w = (unsigned)f2h(b.z) | ((unsigned)f2h(b.w) << 16);
    *(uint4*)(outp + i) = o;
}

// ---------- CSR build, XCD-privatized ----------
__global__ void count64(const int* __restrict__ ei, const float* __restrict__ ew,
                        unsigned long long* __restrict__ bins) {
    int e = blockIdx.x * 256 + threadIdx.x;
    int d = ei[EE + e];
    unsigned long long v = (1ULL << 40) |
        (unsigned long long)(unsigned int)__float2uint_rn(ew[e] * 16777216.0f);
    atomicAdd(&bins[(size_t)(blockIdx.x & 7) * NN + d], v);
}

__global__ void scan_block_bins(const unsigned long long* __restrict__ bins,
                                int* __restrict__ rowptr, int* __restrict__ bsum,
                                float* __restrict__ rsqd, float* __restrict__ invdeg) {
    __shared__ int sd[256];
    int t = threadIdx.x;
    int i = blockIdx.x * 256 + t;
    unsigned long long s = 0;
    #pragma unroll
    for (int x = 0; x < 8; x++) s += bins[(size_t)x * NN + i];
    int v = (int)(s >> 40);
    float deg = 1.f + (float)(s & ((1ULL << 40) - 1)) * (1.f / 16777216.f);
    rsqd[i] = rsqrtf(deg);
    invdeg[i] = 1.f / deg;
    sd[t] = v;
    __syncthreads();
    #pragma unroll
    for (int off = 1; off < 256; off <<= 1) {
        int add = (t >= off) ? sd[t - off] : 0;
        __syncthreads();
        sd[t] += add;
        __syncthreads();
    }
    rowptr[i] = sd[t] - v;
    if (t == 255) bsum[blockIdx.x] = sd[255];
}

__global__ void scan_partials(int* __restrict__ bsum) {
    __shared__ int sd[1024];
    int t = threadIdx.x;
    int v = bsum[t];
    sd[t] = v;
    __syncthreads();
    #pragma unroll
    for (int off = 1; off < 1024; off <<= 1) {
        int add = (t >= off) ? sd[t - off] : 0;
        __syncthreads();
        sd[t] += add;
        __syncthreads();
    }
    bsum[t] = sd[t] - v;
}

__global__ void scan_add(int* __restrict__ rowptr, const int* __restrict__ bsum) {
    int i = blockIdx.x * 256 + threadIdx.x;
    rowptr[i] += bsum[blockIdx.x];
    if (i == 0) rowptr[NN] = EE;
}

__global__ void cursor_init(const unsigned long long* __restrict__ bins,
                            const int* __restrict__ rowptr, int* __restrict__ cursor) {
    int n = blockIdx.x * 256 + threadIdx.x;
    int base = rowptr[n];
    #pragma unroll
    for (int x = 0; x < 8; x++) {
        cursor[(size_t)x * NN + n] = base;
        base += (int)(bins[(size_t)x * NN + n] >> 40);
    }
}

__global__ void scatter_edges(const int* __restrict__ ei, const float* __restrict__ ew,
                              const float* __restrict__ rsqd, int* __restrict__ cursor,
                              int2* __restrict__ evw) {
    int e = blockIdx.x * 256 + threadIdx.x;
    int s = ei[e];
    int d = ei[EE + e];
    float wt = ew[e] * rsqd[s];
    int pos = atomicAdd(&cursor[(size_t)(blockIdx.x & 7) * NN + d], 1);
    evw[pos] = make_int2(s, __float_as_int(wt));
}

// ---------- layer-0 scores ----------
__global__ void scores0_kernel(const float* __restrict__ x, const float* __restrict__ pn0,
                               float* __restrict__ scores) {
    __shared__ float p[32];
    if (threadIdx.x < 32) p[threadIdx.x] = pn0[threadIdx.x];
    __syncthreads();
    int n = blockIdx.x * 256 + threadIdx.x;
    const float4* xr = (const float4*)(x + (size_t)n * 32);
    float s = 0.f;
    #pragma unroll
    for (int j = 0; j < 8; j++) {
        float4 v = xr[j];
        s += v.x * p[j * 4] + v.y * p[j * 4 + 1] + v.z * p[j * 4 + 2] + v.w * p[j * 4 + 3];
    }
    scores[n] = s;
}

// ---------- per-graph top-7 ----------
__global__ void topk_kernel(const float* __restrict__ scores, float* __restrict__ topv,
                            int* __restrict__ topi) {
    int g = blockIdx.x;
    int t = threadIdx.x;
    float lv[KK];
    int li[KK];
    #pragma unroll
    for (int j = 0; j < KK; j++) { lv[j] = -INFINITY; li[j] = 0; }
    const float* sg = scores + (size_t)g * NPER;
    for (int it = 0; it < NPER / 256; ++it) {
        int idx = it * 256 + t;
        float v = sg[idx];
        if (v > lv[KK - 1]) {
            int j = KK - 1;
            while (j > 0 && lv[j - 1] < v) { lv[j] = lv[j - 1]; li[j] = li[j - 1]; j--; }
            lv[j] = v; li[j] = idx;
        }
    }
    __shared__ float sval[256];
    __shared__ int sidx[256];
    __shared__ int swin;
    int cons = 0;
    for (int r = 0; r < KK; r++) {
        sval[t] = (cons < KK) ? lv[cons] : -INFINITY;
        sidx[t] = t;
        __syncthreads();
        for (int s = 128; s > 0; s >>= 1) {
            if (t < s) {
                if (sval[t + s] > sval[t]) { sval[t] = sval[t + s]; sidx[t] = sidx[t + s]; }
            }
            __syncthreads();
        }
        if (t == 0) swin = sidx[0];
        __syncthreads();
        if (t == swin) {
            topv[g * KK + r] = lv[cons];
            topi[g * KK + r] = g * NPER + li[cons];
            cons++;
        }
        __syncthreads();
    }
}

// ---------- Z = mean_k tanh(s)*h[idx] (f32 source, layer 0) ----------
__global__ void z_kernel(const float* __restrict__ h, int din, const float* __restrict__ topv,
                         const int* __restrict__ topi, float* __restrict__ Z) {
    int b = blockIdx.x;
    int d = threadIdx.x;
    if (d >= din) return;
    float acc = 0.f;
    for (int j = 0; j < KK; j++) {
        acc += tanhf(topv[b * KK + j]) * h[(size_t)topi[b * KK + j] * din + d];
    }
    Z[b * din + d] = acc * (1.f / 7.f);
}

// ---------- Z from f16 source (layer 1) ----------
__global__ void z_kernel_h(const unsigned short* __restrict__ h, int din,
                           const float* __restrict__ topv, const int* __restrict__ topi,
                           float* __restrict__ Z) {
    int b = blockIdx.x;
    int d = threadIdx.x;
    if (d >= din) return;
    float acc = 0.f;
    for (int j = 0; j < KK; j++) {
        acc += tanhf(topv[b * KK + j]) * h2f(h[(size_t)topi[b * KK + j] * din + d]);
    }
    Z[b * din + d] = acc * (1.f / 7.f);
}

// ---------- GRU: ghl[j,b] = sum_k Whh[j,k]*gh[b,k] ----------
__global__ void gru_matvec(const float* __restrict__ Whh, const float* __restrict__ gh,
                           float* __restrict__ ghl, int P) {
    int t = threadIdx.x;
    int g = t >> 4, l16 = t & 15;
    int row = blockIdx.x * 16 + g;
    int k0 = blockIdx.y * 512;
    float acc[16];
    #pragma unroll
    for (int b = 0; b < 16; b++) acc[b] = 0.f;
    const float* wr = Whh + (size_t)row * P + k0 + l16 * 4;
    const float* gr = gh + k0 + l16 * 4;
    #pragma unroll 2
    for (int kk = 0; kk < 8; ++kk) {
        float4 a = *(const float4*)(wr + kk * 64);
        #pragma unroll
        for (int b = 0; b < 16; b++) {
            float4 gv = *(const float4*)(gr + (size_t)b * P + kk * 64);
            acc[b] += a.x * gv.x + a.y * gv.y + a.z * gv.z + a.w * gv.w;
        }
    }
    #pragma unroll
    for (int b = 0; b < 16; b++) {
        float v = acc[b];
        v += __shfl_xor(v, 1); v += __shfl_xor(v, 2);
        v += __shfl_xor(v, 4); v += __shfl_xor(v, 8);
        if (l16 == b) atomicAdd(&ghl[(size_t)row * 16 + b], v);
    }
}

// ---------- GRU gates + evolved-W mean ----------
__global__ void gate_kernel(const float* __restrict__ Wih, const float* __restrict__ bih,
                            const float* __restrict__ bhh, const float* __restrict__ gh,
                            const float* __restrict__ ghl, const float* __restrict__ Zg,
                            float* __restrict__ Wev, int P, int din) {
    __shared__ float Zs[16 * 64];
    int t = threadIdx.x;
    for (int idx = t; idx < 16 * din; idx += 256) Zs[idx] = Zg[idx];
    __syncthreads();
    int p = blockIdx.x * 256 + t;
    float br = bih[p], bz = bih[P + p], bn = bih[2 * P + p];
    float bhr = bhh[p], bhz = bhh[P + p], bhn = bhh[2 * P + p];
    const float* w_r = Wih + (size_t)p * din;
    const float* w_z = Wih + (size_t)(P + p) * din;
    const float* w_n = Wih + (size_t)(2 * P + p) * din;
    float wsum = 0.f;
    for (int b = 0; b < 16; b++) {
        float ir = br, iz = bz, inn = bn;
        for (int d = 0; d < din; ++d) {
            float zd = Zs[b * din + d];
            ir += w_r[d] * zd;
            iz += w_z[d] * zd;
            inn += w_n[d] * zd;
        }
        float hr = ghl[(size_t)p * 16 + b] + bhr;
        float hz = ghl[(size_t)(P + p) * 16 + b] + bhz;
        float hn = ghl[(size_t)(2 * P + p) * 16 + b] + bhn;
        float r = 1.f / (1.f + expf(-(ir + hr)));
        float z = 1.f / (1.f + expf(-(iz + hz)));
        float n = tanhf(inn + r * hn);
        float hprev = gh[(size_t)b * P + p];
        wsum += (1.f - z) * n + z * hprev;
    }
    Wev[p] = wsum * (1.f / 16.f);
}

// ---------- edge aggregation over f16 rows: LSH=5 -> 32 lanes/node, LSH=6 -> 64 ----------
template<int DIN, int LSH>
__global__ void agg_kernel(const unsigned short* __restrict__ hin,
                           const int* __restrict__ rowptr, const int2* __restrict__ evw,
                           const float* __restrict__ rsqd, const float* __restrict__ invdeg,
                           float* __restrict__ agg, float* __restrict__ cc) {
    int t = threadIdx.x;
    int lane = t & ((1 << LSH) - 1);
    int i = blockIdx.x * (256 >> LSH) + (t >> LSH);
    int e0 = rowptr[i], e1 = rowptr[i + 1];
    float acc = 0.f, csum = 0.f;
    for (int e = e0; e < e1; e += 8) {
        int2 ev[8];
        #pragma unroll
        for (int j = 0; j < 8; j++) {
            ev[j] = (e + j < e1) ? evw[e + j] : make_int2(i, 0);
        }
        float v[8];
        #pragma unroll
        for (int j = 0; j < 8; j++) {
            v[j] = h2f(hin[(size_t)ev[j].x * DIN + lane]);
        }
        #pragma unroll
        for (int j = 0; j < 8; j++) {
            float nw = __int_as_float(ev[j].y);
            csum += nw;
            acc += nw * v[j];
        }
    }
    float rsi = rsqd[i];
    float idg = invdeg[i];
    float r = acc * rsi + h2f(hin[(size_t)i * DIN + lane]) * idg;
    agg[(size_t)i * DIN + lane] = r;
    #pragma unroll
    for (int o = (1 << LSH) >> 1; o > 0; o >>= 1) csum += __shfl_xor(csum, o);
    if (lane == 0) cc[i] = csum * rsi + idg;
}

// ---------- post kernels: 1 wave = 64-node tile, lane = outdim ----------
__global__ __launch_bounds__(64) void post0_kernel(
    const float* __restrict__ agg, const float* __restrict__ cc,
    const float* __restrict__ Wev, const float* __restrict__ gcnb,
    const float* __restrict__ lng, const float* __restrict__ lnb,
    const float* __restrict__ pn1, unsigned short* __restrict__ h1h,
    float* __restrict__ scores) {
    __shared__ float tile[64 * TPAD];
    const int lane = threadIdx.x;
    const int tb = blockIdx.x * 64;
    const int j = lane & 15, q = lane >> 4;
    float v0[16], v1[16], v2[16], v3[16];
    #pragma unroll
    for (int k = 0; k < 16; k++) { v0[k] = 0.f; v1[k] = 0.f; v2[k] = 0.f; v3[k] = 0.f; }
    for (int db = 0; db < 8; ++db) {
        float wc0 = Wev[(db * 4 + 0) * 64 + lane];
        float wc1 = Wev[(db * 4 + 1) * 64 + lane];
        float wc2 = Wev[(db * 4 + 2) * 64 + lane];
        float wc3 = Wev[(db * 4 + 3) * 64 + lane];
        #pragma unroll
        for (int k = 0; k < 16; k++) {
            float4 a = *(const float4*)(agg + (size_t)(tb + k) * 32 + db * 4);
            v0[k] += a.x * wc0 + a.y * wc1 + a.z * wc2 + a.w * wc3;
        }
        #pragma unroll
        for (int k = 0; k < 16; k++) {
            float4 a = *(const float4*)(agg + (size_t)(tb + 16 + k) * 32 + db * 4);
            v1[k] += a.x * wc0 + a.y * wc1 + a.z * wc2 + a.w * wc3;
        }
        #pragma unroll
        for (int k = 0; k < 16; k++) {
            float4 a = *(const float4*)(agg + (size_t)(tb + 32 + k) * 32 + db * 4);
            v2[k] += a.x * wc0 + a.y * wc1 + a.z * wc2 + a.w * wc3;
        }
        #pragma unroll
        for (int k = 0; k < 16; k++) {
            float4 a = *(const float4*)(agg + (size_t)(tb + 48 + k) * 32 + db * 4);
            v3[k] += a.x * wc0 + a.y * wc1 + a.z * wc2 + a.w * wc3;
        }
    }
    float gL = gcnb[lane];
    float lgv[16], lbv[16], pnv[16];
    #pragma unroll
    for (int r = 0; r < 16; r++) {
        lgv[r] = lng[q * 16 + r];
        lbv[r] = lnb[q * 16 + r];
        pnv[r] = pn1[q * 16 + r];
    }
    float* trow = tile + lane * TPAD;
    auto do_chunk = [&](float (&VV)[16], int C) {
        __syncthreads();
        #pragma unroll
        for (int k = 0; k < 16; k++) trow[k] = VV[k] + gL * cc[tb + C * 16 + k];
        __syncthreads();
        float av[16];
        #pragma unroll
        for (int r = 0; r < 16; r++) av[r] = tile[(q * 16 + r) * TPAD + j];
        float s1 = 0.f, s2 = 0.f;
        #pragma unroll
        for (int r = 0; r < 16; r++) { s1 += av[r]; s2 += av[r] * av[r]; }
        s1 += __shfl_xor(s1, 16); s1 += __shfl_xor(s1, 32);
        s2 += __shfl_xor(s2, 16); s2 += __shfl_xor(s2, 32);
        float mu = s1 * (1.f / 64.f);
        float rstd = rsqrtf(s2 * (1.f / 64.f) - mu * mu + 1e-5f);
        float hv[16];
        float sc = 0.f;
        #pragma unroll
        for (int r = 0; r < 16; r++) {
            hv[r] = fmaxf((av[r] - mu) * rstd * lgv[r] + lbv[r], 0.f);
            sc += hv[r] * pnv[r];
        }
        int node = tb + C * 16 + j;
        uint4 o0, o1;
        o0.x = (unsigned)f2h(hv[0])  | ((unsigned)f2h(hv[1])  << 16);
        o0.y = (unsigned)f2h(hv[2])  | ((unsigned)f2h(hv[3])  << 16);
        o0.z = (unsigned)f2h(hv[4])  | ((unsigned)f2h(hv[5])  << 16);
        o0.w = (unsigned)f2h(hv[6])  | ((unsigned)f2h(hv[7])  << 16);
        o1.x = (unsigned)f2h(hv[8])  | ((unsigned)f2h(hv[9])  << 16);
        o1.y = (unsigned)f2h(hv[10]) | ((unsigned)f2h(hv[11]) << 16);
        o1.z = (unsigned)f2h(hv[12]) | ((unsigned)f2h(hv[13]) << 16);
        o1.w = (unsigned)f2h(hv[14]) | ((unsigned)f2h(hv[15]) << 16);
        *(uint4*)(h1h + (size_t)node * 64 + q * 16) = o0;
        *(uint4*)(h1h + (size_t)node * 64 + q * 16 + 8) = o1;
        sc += __shfl_xor(sc, 16); sc += __shfl_xor(sc, 32);
        if (q == 0) scores[node] = sc;
    };
    do_chunk(v0, 0); do_chunk(v1, 1); do_chunk(v2, 2); do_chunk(v3, 3);
}

__global__ __launch_bounds__(64) void post1_kernel(
    const float* __restrict__ agg, const float* __restrict__ cc,
    const float* __restrict__ Wev, const float* __restrict__ gcnb,
    const float* __restrict__ lng, const float* __restrict__ lnb,
    const float* __restrict__ Wp, const float* __restrict__ bp,
    float* __restrict__ out) {
    __shared__ float tile[64 * TPAD];
    const int lane = threadIdx.x;
    const int tb = blockIdx.x * 64;
    const int j = lane & 15, q = lane >> 4;
    float v0[16], v1[16], v2[16], v3[16];
    #pragma unroll
    for (int k = 0; k < 16; k++) { v0[k] = 0.f; v1[k] = 0.f; v2[k] = 0.f; v3[k] = 0.f; }
    for (int db = 0; db < 16; ++db) {
        float wc0 = Wev[(db * 4 + 0) * 64 + lane];
        float wc1 = Wev[(db * 4 + 1) * 64 + lane];
        float wc2 = Wev[(db * 4 + 2) * 64 + lane];
        float wc3 = Wev[(db * 4 + 3) * 64 + lane];
        #pragma unroll
        for (int k = 0; k < 16; k++) {
            float4 a = *(const float4*)(agg + (size_t)(tb + k) * 64 + db * 4);
            v0[k] += a.x * wc0 + a.y * wc1 + a.z * wc2 + a.w * wc3;
        }
        #pragma unroll
        for (int k = 0; k < 16; k++) {
            float4 a = *(const float4*)(agg + (size_t)(tb + 16 + k) * 64 + db * 4);
            v1[k] += a.x * wc0 + a.y * wc1 + a.z * wc2 + a.w * wc3;
        }
        #pragma unroll
        for (int k = 0; k < 16; k++) {
            float4 a = *(const float4*)(agg + (size_t)(tb + 32 + k) * 64 + db * 4);
            v2[k] += a.x * wc0 + a.y * wc1 + a.z * wc2 + a.w * wc3;
        }
        #pragma unroll
        for (int k = 0; k < 16; k++) {
            float4 a = *(const float4*)(agg + (size_t)(tb + 48 + k) * 64 + db * 4);
            v3[k] += a.x * wc0 + a.y * wc1 + a.z * wc2 + a.w * wc3;
        }
    }
    float gL = gcnb[lane];
    float lgv[16], lbv[16];
    #pragma unroll
    for (int r = 0; r < 16; r++) {
        lgv[r] = lng[q * 16 + r];
        lbv[r] = lnb[q * 16 + r];
    }
    float bpv[10];
    #pragma unroll
    for (int t2 = 0; t2 < 10; t2++) bpv[t2] = bp[t2];
    float* trow = tile + lane * TPAD;
    auto do_chunk = [&](float (&VV)[16], int C) {
        __syncthreads();
        #pragma unroll
        for (int k = 0; k < 16; k++) trow[k] = VV[k] + gL * cc[tb + C * 16 + k];
        __syncthreads();
        float av[16];
        #pragma unroll
        for (int r = 0; r < 16; r++) av[r] = tile[(q * 16 + r) * TPAD + j];
        float s1 = 0.f, s2 = 0.f;
        #pragma unroll
        for (int r = 0; r < 16; r++) { s1 += av[r]; s2 += av[r] * av[r]; }
        s1 += __shfl_xor(s1, 16); s1 += __shfl_xor(s1, 32);
        s2 += __shfl_xor(s2, 16); s2 += __shfl_xor(s2, 32);
        float mu = s1 * (1.f / 64.f);
        float rstd = rsqrtf(s2 * (1.f / 64.f) - mu * mu + 1e-5f);
        float hv[16];
        #pragma unroll
        for (int r = 0; r < 16; r++)
            hv[r] = fmaxf((av[r] - mu) * rstd * lgv[r] + lbv[r], 0.f);
        float oa[10];
        #pragma unroll
        for (int t2 = 0; t2 < 10; t2++) oa[t2] = 0.f;
        #pragma unroll
        for (int r = 0; r < 16; r++) {
            const float* wpb = Wp + (size_t)(q * 16 + r) * 2;
            float2 w0 = *(const float2*)(wpb);
            float2 w1 = *(const float2*)(wpb + 128);
            float2 w2 = *(const float2*)(wpb + 256);
            float2 w3 = *(const float2*)(wpb + 384);
            float2 w4 = *(const float2*)(wpb + 512);
            oa[0] += hv[r] * w0.x; oa[1] += hv[r] * w0.y;
            oa[2] += hv[r] * w1.x; oa[3] += hv[r] * w1.y;
            oa[4] += hv[r] * w2.x; oa[5] += hv[r] * w2.y;
            oa[6] += hv[r] * w3.x; oa[7] += hv[r] * w3.y;
            oa[8] += hv[r] * w4.x; oa[9] += hv[r] * w4.y;
        }
        #pragma unroll
        for (int t2 = 0; t2 < 10; t2++) {
            oa[t2] += __shfl_xor(oa[t2], 16);
            oa[t2] += __shfl_xor(oa[t2], 32);
        }
        if (q == 0) {
            int node = tb + C * 16 + j;
            #pragma unroll
            for (int t2 = 0; t2 < 10; t2++) out[(size_t)node * 10 + t2] = oa[t2] + bpv[t2];
        }
    };
    do_chunk(v0, 0); do_chunk(v1, 1); do_chunk(v2, 2); do_chunk(v3, 3);
}

extern "C" void kernel_launch(void* const* d_in, const int* in_sizes, int n_in,
                              void* d_out, int out_size, void* d_ws, size_t ws_size,
                              hipStream_t stream) {
    const float* x     = (const float*)d_in[0];
    const int*   ei    = (const int*)d_in[1];
    const float* ew    = (const float*)d_in[2];
    const float* p0    = (const float*)d_in[5];
    const float* p1    = (const float*)d_in[6];
    const float* Wih0  = (const float*)d_in[7];
    const float* Whh0  = (const float*)d_in[8];
    const float* bih0  = (const float*)d_in[9];
    const float* bhh0  = (const float*)d_in[10];
    const float* Wih1  = (const float*)d_in[11];
    const float* Whh1  = (const float*)d_in[12];
    const float* bih1  = (const float*)d_in[13];
    const float* bhh1  = (const float*)d_in[14];
    const float* gruh0 = (const float*)d_in[15];
    const float* gruh1 = (const float*)d_in[16];
    const float* gcnb0 = (const float*)d_in[17];
    const float* gcnb1 = (const float*)d_in[18];
    const float* lng0  = (const float*)d_in[19];
    const float* lnb0  = (const float*)d_in[20];
    const float* lng1  = (const float*)d_in[21];
    const float* lnb1  = (const float*)d_in[22];
    const float* Wp    = (const float*)d_in[23];
    const float* bp    = (const float*)d_in[24];
    float* out = (float*)d_out;

    // workspace carve
    char* w = (char*)d_ws;
    size_t off = 0;
    auto alloc = [&](size_t bytes) -> void* {
        void* p = w + off;
        off += (bytes + 255) & ~(size_t)255;
        return p;
    };
    int*   rowptr = (int*)alloc((NN + 1) * sizeof(int));
    int2*  evw    = (int2*)alloc((size_t)EE * sizeof(int2));
    float* rsqd   = (float*)alloc(NN * sizeof(float));
    float* invdeg = (float*)alloc(NN * sizeof(float));
    float* scores = (float*)alloc(NN * sizeof(float));
    float* topv   = (float*)alloc(NG * KK * sizeof(float));
    int*   topi   = (int*)alloc(NG * KK * sizeof(int));
    float* Z      = (float*)alloc(16 * 64 * sizeof(float));
    float* ghl    = (float*)alloc((size_t)12288 * 16 * sizeof(float));
    float* Wev    = (float*)alloc(4096 * sizeof(float));
    float* cc     = (float*)alloc(NN * sizeof(float));
    float* agg    = (float*)alloc((size_t)NN * 64 * sizeof(float));
    unsigned short* xh  = (unsigned short*)alloc((size_t)NN * 32 * sizeof(unsigned short));
    unsigned short* h1h = (unsigned short*)alloc((size_t)NN * 64 * sizeof(unsigned short));
    float* pn     = (float*)alloc(96 * sizeof(float));
    int*   bsum   = (int*)alloc(1024 * sizeof(int));

    // bins64 (16 MB) + cursor (8 MB) alias into agg's 67 MB (dead before agg is written)
    unsigned long long* bins64 = (unsigned long long*)agg;
    int* cursor = (int*)((char*)agg + (size_t)8 * NN * sizeof(unsigned long long));

    // --- CSR build (shared by both layers), XCD-privatized ---
    hipMemsetAsync(bins64, 0, (size_t)8 * NN * sizeof(unsigned long long), stream);
    prep_p<<<1, 64, 0, stream>>>(p0, p1, pn);
    to_f16<<<NN * 32 / 8 / 256, 256, 0, stream>>>(x, xh);
    count64<<<EE / 256, 256, 0, stream>>>(ei, ew, bins64);
    scan_block_bins<<<NN / 256, 256, 0, stream>>>(bins64, rowptr, bsum, rsqd, invdeg);
    scan_partials<<<1, 1024, 0, stream>>>(bsum);
    scan_add<<<NN / 256, 256, 0, stream>>>(rowptr, bsum);
    cursor_init<<<NN / 256, 256, 0, stream>>>(bins64, rowptr, cursor);
    scatter_edges<<<EE / 256, 256, 0, stream>>>(ei, ew, rsqd, cursor, evw);

    // --- layer 0 ---
    scores0_kernel<<<NN / 256, 256, 0, stream>>>(x, pn, scores);
    topk_kernel<<<NG, 256, 0, stream>>>(scores, topv, topi);
    z_kernel<<<NG, 32, 0, stream>>>(x, 32, topv, topi, Z);
    hipMemsetAsync(ghl, 0, (size_t)6144 * 16 * sizeof(float), stream);
    gru_matvec<<<dim3(6144 / 16, 4), 256, 0, stream>>>(Whh0, gruh0, ghl, 2048);
    gate_kernel<<<2048 / 256, 256, 0, stream>>>(Wih0, bih0, bhh0, gruh0, ghl, Z, Wev, 2048, 32);
    agg_kernel<32, 5><<<NN / 8, 256, 0, stream>>>(xh, rowptr, evw, rsqd, invdeg, agg, cc);
    post0_kernel<<<NN / 64, 64, 0, stream>>>(agg, cc, Wev, gcnb0, lng0, lnb0, pn + 32, h1h, scores);

    // --- layer 1 ---
    topk_kernel<<<NG, 256, 0, stream>>>(scores, topv, topi);
    z_kernel_h<<<NG, 64, 0, stream>>>(h1h, 64, topv, topi, Z);
    hipMemsetAsync(ghl, 0, (size_t)12288 * 16 * sizeof(float), stream);
    gru_matvec<<<dim3(12288 / 16, 8), 256, 0, stream>>>(Whh1, gruh1, ghl, 4096);
    gate_kernel<<<4096 / 256, 256, 0, stream>>>(Wih1, bih1, bhh1, gruh1, ghl, Z, Wev, 4096, 64);
    agg_kernel<64, 6><<<NN / 4, 256, 0, stream>>>(h1h, rowptr, evw, rsqd, invdeg, agg, cc);
    post1_kernel<<<NN / 64, 64, 0, stream>>>(agg, cc, Wev, gcnb1, lng1, lnb1, Wp, bp, out);
}